// Round 1
// baseline (1152.360 us; speedup 1.0000x reference)
//
#include <hip/hip_runtime.h>

#define NFULL 4096
#define CDIM  512
#define HEADS 8
#define DDIM  64

__device__ __forceinline__ float dot4(float4 a, float4 b) {
  return a.x * b.x + a.y * b.y + a.z * b.z + a.w * b.w;
}

// K1: t[4096][96] = x @ [q_w1; kv_w1]^T   (cols 0..31 = q_w1, 32..95 = kv_w1)
__global__ __launch_bounds__(256) void k_proj1(const float* __restrict__ x,
                                               const float* __restrict__ qw1,
                                               const float* __restrict__ kvw1,
                                               float* __restrict__ t) {
  __shared__ __align__(16) float xs[16][516];
  const int r0 = blockIdx.x * 16;
  for (int idx = threadIdx.x; idx < 16 * 512; idx += 256)
    xs[idx >> 9][idx & 511] = x[(r0 + (idx >> 9)) * 512 + (idx & 511)];
  __syncthreads();
  const int r = threadIdx.x >> 4;
  const int cb = threadIdx.x & 15;
  for (int k = 0; k < 6; ++k) {
    const int c = cb + 16 * k;  // 0..95
    const float* __restrict__ w = (c < 32) ? (qw1 + c * 512) : (kvw1 + (c - 32) * 512);
    float acc = 0.f;
    for (int e = 0; e < 512; e += 4)
      acc += dot4(*(const float4*)&xs[r][e], *(const float4*)&w[e]);
    t[(r0 + r) * 96 + c] = acc;
  }
}

// K2: q = 8 * t_q @ q_w2^T -> qh[H][N][D];  kv = t_kv @ kv_w2^T -> kh, vh [H][N][D]
__global__ __launch_bounds__(256) void k_proj2(const float* __restrict__ t,
                                               const float* __restrict__ qw2,
                                               const float* __restrict__ kvw2,
                                               float* __restrict__ qh,
                                               float* __restrict__ kh,
                                               float* __restrict__ vh) {
  __shared__ __align__(16) float ts[16][100];
  const int r0 = blockIdx.x * 16;
  for (int idx = threadIdx.x; idx < 16 * 96; idx += 256) {
    const int r = idx / 96, c = idx - r * 96;
    ts[r][c] = t[(r0 + r) * 96 + c];
  }
  __syncthreads();
  const int r = threadIdx.x >> 4;
  const int cb = threadIdx.x & 15;
  const int row = r0 + r;
  for (int k = 0; k < 96; ++k) {
    const int c = cb + 16 * k;  // 0..1535
    if (c < 512) {
      const float* __restrict__ w = qw2 + c * 32;
      float acc = 0.f;
      for (int e = 0; e < 32; e += 4)
        acc += dot4(*(const float4*)&ts[r][e], *(const float4*)&w[e]);
      acc *= 8.0f;  // SCALE = sqrt(64)
      qh[((c >> 6) * NFULL + row) * 64 + (c & 63)] = acc;
    } else {
      const int cc = c - 512;  // 0..1023
      const float* __restrict__ w = kvw2 + cc * 64;
      float acc = 0.f;
      for (int e = 0; e < 64; e += 4)
        acc += dot4(*(const float4*)&ts[r][32 + e], *(const float4*)&w[e]);
      if (cc < 512)
        kh[((cc >> 6) * NFULL + row) * 64 + (cc & 63)] = acc;
      else {
        const int c2 = cc - 512;
        vh[((c2 >> 6) * NFULL + row) * 64 + (c2 & 63)] = acc;
      }
    }
  }
}

// K3: per (head, 64-query tile): full-row softmax stats over all 4096 keys,
// then block-diag-causal numerator (<=16 keys per query). wv written [N][C].
__global__ __launch_bounds__(256) void k_attn(const float* __restrict__ qh,
                                              const float* __restrict__ kh,
                                              const float* __restrict__ vh,
                                              float* __restrict__ wv) {
  __shared__ __align__(16) float Qs[64][68];
  __shared__ __align__(16) float Ks[64][68];
  __shared__ float Ms[64][17];
  __shared__ float Ls[64][17];
  const int h = blockIdx.x >> 6;
  const int qt = blockIdx.x & 63;
  const int q0 = qt * 64;
  const float* __restrict__ Q = qh + (h * NFULL + q0) * 64;
  for (int idx = threadIdx.x; idx < 64 * 64; idx += 256)
    Qs[idx >> 6][idx & 63] = Q[idx];

  const int qg = threadIdx.x >> 4;  // 0..15 -> queries qg*4..+3
  const int kg = threadIdx.x & 15;  // 0..15 -> keys kg*4..+3 (per tile)
  float m[4] = {-1e30f, -1e30f, -1e30f, -1e30f};
  float l[4] = {0.f, 0.f, 0.f, 0.f};

  for (int kt = 0; kt < 64; ++kt) {
    __syncthreads();  // protect Ks overwrite; covers Qs load on kt==0 path below
    const float* __restrict__ K = kh + (h * NFULL + kt * 64) * 64;
    for (int idx = threadIdx.x; idx < 64 * 64; idx += 256)
      Ks[idx >> 6][idx & 63] = K[idx];
    __syncthreads();

    float s[4][4];
#pragma unroll
    for (int i = 0; i < 4; ++i)
#pragma unroll
      for (int j = 0; j < 4; ++j) s[i][j] = 0.f;

    for (int e = 0; e < 64; e += 4) {
      float4 qv[4], kv[4];
#pragma unroll
      for (int i = 0; i < 4; ++i) qv[i] = *(const float4*)&Qs[qg * 4 + i][e];
#pragma unroll
      for (int j = 0; j < 4; ++j) kv[j] = *(const float4*)&Ks[kg * 4 + j][e];
#pragma unroll
      for (int i = 0; i < 4; ++i)
#pragma unroll
        for (int j = 0; j < 4; ++j) s[i][j] += dot4(qv[i], kv[j]);
    }

#pragma unroll
    for (int i = 0; i < 4; ++i) {
      const float mx = fmaxf(fmaxf(s[i][0], s[i][1]), fmaxf(s[i][2], s[i][3]));
      if (mx > m[i]) {
        l[i] *= __expf(m[i] - mx);
        m[i] = mx;
      }
#pragma unroll
      for (int j = 0; j < 4; ++j) l[i] += __expf(s[i][j] - m[i]);
    }
  }

#pragma unroll
  for (int i = 0; i < 4; ++i) {
    Ms[qg * 4 + i][kg] = m[i];
    Ls[qg * 4 + i][kg] = l[i];
  }
  __syncthreads();
  if (threadIdx.x < 64) {
    const int r = threadIdx.x;
    float mm = -1e30f;
    for (int g = 0; g < 16; ++g) mm = fmaxf(mm, Ms[r][g]);
    float ll = 0.f;
    for (int g = 0; g < 16; ++g) ll += Ls[r][g] * __expf(Ms[r][g] - mm);
    Ms[r][16] = mm;
    Ls[r][16] = ll;
  }
  __syncthreads();

  // phase 2: reload K rows of this tile's own 64-range (mask block lives inside it)
  const float* __restrict__ K2 = kh + (h * NFULL + q0) * 64;
  for (int idx = threadIdx.x; idx < 64 * 64; idx += 256)
    Ks[idx >> 6][idx & 63] = K2[idx];
  __syncthreads();

  const int r = threadIdx.x >> 2;  // query 0..63
  const int dq = threadIdx.x & 3;  // 16-wide d chunk
  const float mm = Ms[r][16];
  const float inv_ll = 1.0f / Ls[r][16];
  const int jb = (r >> 4) << 4;    // local 16-block start
  const int nj = (r & 15) + 1;     // causal within block
  const float* __restrict__ V = vh + (h * NFULL + q0) * 64;

  float acc[16];
#pragma unroll
  for (int dd = 0; dd < 16; ++dd) acc[dd] = 0.f;

  for (int jj = 0; jj < nj; ++jj) {
    const int j = jb + jj;
    float s = 0.f;
    for (int e = 0; e < 64; e += 4)
      s += dot4(*(const float4*)&Qs[r][e], *(const float4*)&Ks[j][e]);
    const float w = __expf(s - mm) * inv_ll;
    const float4* vrow = (const float4*)(V + j * 64 + dq * 16);
#pragma unroll
    for (int dd = 0; dd < 4; ++dd) {
      const float4 vv = vrow[dd];
      acc[dd * 4 + 0] += w * vv.x;
      acc[dd * 4 + 1] += w * vv.y;
      acc[dd * 4 + 2] += w * vv.z;
      acc[dd * 4 + 3] += w * vv.w;
    }
  }
  float* o = wv + (q0 + r) * CDIM + h * 64 + dq * 16;
#pragma unroll
  for (int dd = 0; dd < 16; ++dd) o[dd] = acc[dd];
}

// K4: y = (wv*dw_w + dw_b) @ pw_w^T + pw_b + x
__global__ __launch_bounds__(256) void k_dyn(const float* __restrict__ wvp,
                                             const float* __restrict__ x,
                                             const float* __restrict__ dww,
                                             const float* __restrict__ dwb,
                                             const float* __restrict__ pww,
                                             const float* __restrict__ pwb,
                                             float* __restrict__ y) {
  __shared__ __align__(16) float ds[16][516];
  const int r0 = blockIdx.x * 16;
  for (int idx = threadIdx.x; idx < 16 * 512; idx += 256) {
    const int r = idx >> 9, c = idx & 511;
    ds[r][c] = wvp[(r0 + r) * 512 + c] * dww[c] + dwb[c];
  }
  __syncthreads();
  const int r = threadIdx.x >> 4;
  const int cb = threadIdx.x & 15;
  for (int k = 0; k < 8; ++k) {
    const int c0 = k * 64 + cb * 4;
    const float* __restrict__ w0 = pww + (c0 + 0) * 512;
    const float* __restrict__ w1 = pww + (c0 + 1) * 512;
    const float* __restrict__ w2 = pww + (c0 + 2) * 512;
    const float* __restrict__ w3 = pww + (c0 + 3) * 512;
    float a0 = 0.f, a1 = 0.f, a2 = 0.f, a3 = 0.f;
    for (int e = 0; e < 512; e += 4) {
      const float4 dv = *(const float4*)&ds[r][e];
      a0 += dot4(dv, *(const float4*)&w0[e]);
      a1 += dot4(dv, *(const float4*)&w1[e]);
      a2 += dot4(dv, *(const float4*)&w2[e]);
      a3 += dot4(dv, *(const float4*)&w3[e]);
    }
    const int gi = (r0 + r) * 512 + c0;
    const float4 xv = *(const float4*)&x[gi];
    float4 res;
    res.x = a0 + pwb[c0 + 0] + xv.x;
    res.y = a1 + pwb[c0 + 1] + xv.y;
    res.z = a2 + pwb[c0 + 2] + xv.z;
    res.w = a3 + pwb[c0 + 3] + xv.w;
    *(float4*)&y[gi] = res;
  }
}

// K5a: tp[4096][32] = y @ p_w1^T
__global__ __launch_bounds__(256) void k_pout1(const float* __restrict__ y,
                                               const float* __restrict__ pw1,
                                               float* __restrict__ tp) {
  __shared__ __align__(16) float ys[16][516];
  const int r0 = blockIdx.x * 16;
  for (int idx = threadIdx.x; idx < 16 * 512; idx += 256)
    ys[idx >> 9][idx & 511] = y[(r0 + (idx >> 9)) * 512 + (idx & 511)];
  __syncthreads();
  const int r = threadIdx.x >> 4;
  const int cb = threadIdx.x & 15;
  for (int k = 0; k < 2; ++k) {
    const int c = cb + 16 * k;
    const float* __restrict__ w = pw1 + c * 512;
    float acc = 0.f;
    for (int e = 0; e < 512; e += 4)
      acc += dot4(*(const float4*)&ys[r][e], *(const float4*)&w[e]);
    tp[(r0 + r) * 32 + c] = acc;
  }
}

// K5b: out[4096][512] = tp @ p_w2^T
__global__ __launch_bounds__(256) void k_pout2(const float* __restrict__ tp,
                                               const float* __restrict__ pw2,
                                               float* __restrict__ out) {
  __shared__ __align__(16) float ts[16][36];
  const int r0 = blockIdx.x * 16;
  for (int idx = threadIdx.x; idx < 16 * 32; idx += 256)
    ts[idx >> 5][idx & 31] = tp[(r0 + (idx >> 5)) * 32 + (idx & 31)];
  __syncthreads();
  const int r = threadIdx.x >> 4;
  const int cb = threadIdx.x & 15;
  for (int k = 0; k < 32; ++k) {
    const int c = cb + 16 * k;
    const float* __restrict__ w = pw2 + c * 32;
    float acc = 0.f;
    for (int e = 0; e < 32; e += 4)
      acc += dot4(*(const float4*)&ts[r][e], *(const float4*)&w[e]);
    out[(r0 + r) * 512 + c] = acc;
  }
}

extern "C" void kernel_launch(void* const* d_in, const int* in_sizes, int n_in,
                              void* d_out, int out_size, void* d_ws, size_t ws_size,
                              hipStream_t stream) {
  const float* x     = (const float*)d_in[0];
  const float* q_w1  = (const float*)d_in[1];
  const float* q_w2  = (const float*)d_in[2];
  const float* kv_w1 = (const float*)d_in[3];
  const float* kv_w2 = (const float*)d_in[4];
  const float* dw_w  = (const float*)d_in[5];
  const float* dw_b  = (const float*)d_in[6];
  const float* pw_w  = (const float*)d_in[7];
  const float* pw_b  = (const float*)d_in[8];
  const float* p_w1  = (const float*)d_in[9];
  const float* p_w2  = (const float*)d_in[10];
  float* out = (float*)d_out;

  float* ws = (float*)d_ws;
  float* t  = ws;                       // 4096*96
  float* qh = t + NFULL * 96;           // 8*4096*64
  float* kh = qh + HEADS * NFULL * DDIM;
  float* vh = kh + HEADS * NFULL * DDIM;
  float* wv = vh + HEADS * NFULL * DDIM;  // 4096*512
  float* y  = wv + NFULL * CDIM;          // 4096*512
  float* tp = y + NFULL * CDIM;           // 4096*32

  k_proj1<<<NFULL / 16, 256, 0, stream>>>(x, q_w1, kv_w1, t);
  k_proj2<<<NFULL / 16, 256, 0, stream>>>(t, q_w2, kv_w2, qh, kh, vh);
  k_attn<<<HEADS * (NFULL / 64), 256, 0, stream>>>(qh, kh, vh, wv);
  k_dyn<<<NFULL / 16, 256, 0, stream>>>(wv, x, dw_w, dw_b, pw_w, pw_b, y);
  k_pout1<<<NFULL / 16, 256, 0, stream>>>(y, p_w1, tp);
  k_pout2<<<NFULL / 16, 256, 0, stream>>>(tp, p_w2, out);
}

// Round 2
// 579.787 us; speedup vs baseline: 1.9876x; 1.9876x over previous
//
#include <hip/hip_runtime.h>

#define NFULL 4096
#define CDIM  512
#define HEADS 8
#define DDIM  64

__device__ __forceinline__ float dot4(float4 a, float4 b) {
  return a.x * b.x + a.y * b.y + a.z * b.z + a.w * b.w;
}

// K1: t[4096][96] = x @ [q_w1; kv_w1]^T   (cols 0..31 = q_w1, 32..95 = kv_w1)
// Tiled GEMM: BM=64, O=96, BK=16. Grid 64 blocks, 256 threads, 4x6 per thread.
__global__ __launch_bounds__(256) void k_proj1(const float* __restrict__ x,
                                               const float* __restrict__ qw1,
                                               const float* __restrict__ kvw1,
                                               float* __restrict__ t) {
  __shared__ __align__(16) float As[16][68];   // [k][row]
  __shared__ __align__(16) float Ws[16][100];  // [k][col 0..95]
  const int r0 = blockIdx.x * 64;
  const int ty = threadIdx.x >> 4, tx = threadIdx.x & 15;
  const int lr = threadIdx.x >> 2;          // 0..63
  const int lk = (threadIdx.x & 3) << 2;    // 0,4,8,12
  float acc[4][6];
#pragma unroll
  for (int i = 0; i < 4; ++i)
#pragma unroll
    for (int j = 0; j < 6; ++j) acc[i][j] = 0.f;

  for (int k0 = 0; k0 < 512; k0 += 16) {
    __syncthreads();  // previous tile's reads done
    {  // A tile: 64 rows x 16 k
      const float4 a = *(const float4*)&x[(r0 + lr) * 512 + k0 + lk];
      As[lk + 0][lr] = a.x; As[lk + 1][lr] = a.y;
      As[lk + 2][lr] = a.z; As[lk + 3][lr] = a.w;
    }
    // W tile: 96 cols x 16 k = 384 float4 loads
    for (int idx = threadIdx.x; idx < 384; idx += 256) {
      const int c = idx >> 2;
      const int kk = (idx & 3) << 2;
      const float* __restrict__ wsrc = (c < 32) ? (qw1 + c * 512) : (kvw1 + (c - 32) * 512);
      const float4 w = *(const float4*)&wsrc[k0 + kk];
      Ws[kk + 0][c] = w.x; Ws[kk + 1][c] = w.y;
      Ws[kk + 2][c] = w.z; Ws[kk + 3][c] = w.w;
    }
    __syncthreads();
#pragma unroll
    for (int k = 0; k < 16; ++k) {
      const float4 a = *(const float4*)&As[k][ty * 4];
      const float ar[4] = {a.x, a.y, a.z, a.w};
      float br[6];
#pragma unroll
      for (int j = 0; j < 6; ++j) br[j] = Ws[k][tx + 16 * j];
#pragma unroll
      for (int i = 0; i < 4; ++i)
#pragma unroll
        for (int j = 0; j < 6; ++j) acc[i][j] += ar[i] * br[j];
    }
  }
#pragma unroll
  for (int i = 0; i < 4; ++i)
#pragma unroll
    for (int j = 0; j < 6; ++j)
      t[(r0 + ty * 4 + i) * 96 + tx + 16 * j] = acc[i][j];
}

// K2: q = 8 * t_q @ q_w2^T ; kv = t_kv @ kv_w2^T  -> qh,kh,vh [H][N][D]
// Blocks: 64 rows x 16 cols of the 1536-wide output. Grid 64*96.
__global__ __launch_bounds__(256) void k_proj2(const float* __restrict__ t,
                                               const float* __restrict__ qw2,
                                               const float* __restrict__ kvw2,
                                               float* __restrict__ qh,
                                               float* __restrict__ kh,
                                               float* __restrict__ vh) {
  __shared__ __align__(16) float ts[64][100];
  const int bc = blockIdx.x % 96;
  const int br = blockIdx.x / 96;
  const int r0 = br * 64;
  for (int idx = threadIdx.x; idx < 1536; idx += 256) {
    const int rr = idx / 24;
    const int cc = (idx - rr * 24) * 4;
    *(float4*)&ts[rr][cc] = *(const float4*)&t[(r0 + rr) * 96 + cc];
  }
  __syncthreads();
  const int tx = threadIdx.x & 15, ty = threadIdx.x >> 4;
  const int c = bc * 16 + tx;  // 0..1535 (block-uniform region)
  if (c < 512) {
    const float* __restrict__ w = qw2 + c * 32;
    float4 wr[8];
#pragma unroll
    for (int e = 0; e < 8; ++e) wr[e] = *(const float4*)&w[e * 4];
    const int h = c >> 6, d = c & 63;
#pragma unroll
    for (int i = 0; i < 4; ++i) {
      const int r = ty * 4 + i;
      float acc = 0.f;
#pragma unroll
      for (int e = 0; e < 8; ++e) acc += dot4(*(const float4*)&ts[r][e * 4], wr[e]);
      qh[(h * NFULL + r0 + r) * 64 + d] = acc * 8.0f;  // SCALE
    }
  } else {
    const int cc = c - 512;  // 0..1023
    const float* __restrict__ w = kvw2 + cc * 64;
    float4 wr[16];
#pragma unroll
    for (int e = 0; e < 16; ++e) wr[e] = *(const float4*)&w[e * 4];
    float* __restrict__ dst = (cc < 512) ? kh : vh;
    const int c2 = cc & 511;
    const int h = c2 >> 6, d = c2 & 63;
#pragma unroll
    for (int i = 0; i < 4; ++i) {
      const int r = ty * 4 + i;
      float acc = 0.f;
#pragma unroll
      for (int e = 0; e < 16; ++e) acc += dot4(*(const float4*)&ts[r][32 + e * 4], wr[e]);
      dst[(h * NFULL + r0 + r) * 64 + d] = acc;
    }
  }
}

// K3: per (head, 64-query tile): full-row softmax stats over all 4096 keys,
// then block-diag-causal numerator (<=16 keys per query). wv written [N][C].
__global__ __launch_bounds__(256) void k_attn(const float* __restrict__ qh,
                                              const float* __restrict__ kh,
                                              const float* __restrict__ vh,
                                              float* __restrict__ wv) {
  __shared__ __align__(16) float Qs[64][68];
  __shared__ __align__(16) float Ks[64][68];
  __shared__ float Ms[64][17];
  __shared__ float Ls[64][17];
  const int h = blockIdx.x >> 6;
  const int qt = blockIdx.x & 63;
  const int q0 = qt * 64;
  const float* __restrict__ Q = qh + (h * NFULL + q0) * 64;
  for (int idx = threadIdx.x; idx < 64 * 64; idx += 256)
    Qs[idx >> 6][idx & 63] = Q[idx];

  const int qg = threadIdx.x >> 4;
  const int kg = threadIdx.x & 15;
  float m[4] = {-1e30f, -1e30f, -1e30f, -1e30f};
  float l[4] = {0.f, 0.f, 0.f, 0.f};

  for (int kt = 0; kt < 64; ++kt) {
    __syncthreads();
    const float* __restrict__ K = kh + (h * NFULL + kt * 64) * 64;
    for (int idx = threadIdx.x; idx < 64 * 64; idx += 256)
      Ks[idx >> 6][idx & 63] = K[idx];
    __syncthreads();

    float s[4][4];
#pragma unroll
    for (int i = 0; i < 4; ++i)
#pragma unroll
      for (int j = 0; j < 4; ++j) s[i][j] = 0.f;

    for (int e = 0; e < 64; e += 4) {
      float4 qv[4], kv[4];
#pragma unroll
      for (int i = 0; i < 4; ++i) qv[i] = *(const float4*)&Qs[qg * 4 + i][e];
#pragma unroll
      for (int j = 0; j < 4; ++j) kv[j] = *(const float4*)&Ks[kg * 4 + j][e];
#pragma unroll
      for (int i = 0; i < 4; ++i)
#pragma unroll
        for (int j = 0; j < 4; ++j) s[i][j] += dot4(qv[i], kv[j]);
    }

#pragma unroll
    for (int i = 0; i < 4; ++i) {
      const float mx = fmaxf(fmaxf(s[i][0], s[i][1]), fmaxf(s[i][2], s[i][3]));
      if (mx > m[i]) {
        l[i] *= __expf(m[i] - mx);
        m[i] = mx;
      }
#pragma unroll
      for (int j = 0; j < 4; ++j) l[i] += __expf(s[i][j] - m[i]);
    }
  }

#pragma unroll
  for (int i = 0; i < 4; ++i) {
    Ms[qg * 4 + i][kg] = m[i];
    Ls[qg * 4 + i][kg] = l[i];
  }
  __syncthreads();
  if (threadIdx.x < 64) {
    const int r = threadIdx.x;
    float mm = -1e30f;
    for (int g = 0; g < 16; ++g) mm = fmaxf(mm, Ms[r][g]);
    float ll = 0.f;
    for (int g = 0; g < 16; ++g) ll += Ls[r][g] * __expf(Ms[r][g] - mm);
    Ms[r][16] = mm;
    Ls[r][16] = ll;
  }
  __syncthreads();

  const float* __restrict__ K2 = kh + (h * NFULL + q0) * 64;
  for (int idx = threadIdx.x; idx < 64 * 64; idx += 256)
    Ks[idx >> 6][idx & 63] = K2[idx];
  __syncthreads();

  const int r = threadIdx.x >> 2;
  const int dq = threadIdx.x & 3;
  const float mm = Ms[r][16];
  const float inv_ll = 1.0f / Ls[r][16];
  const int jb = (r >> 4) << 4;
  const int nj = (r & 15) + 1;
  const float* __restrict__ V = vh + (h * NFULL + q0) * 64;

  float acc[16];
#pragma unroll
  for (int dd = 0; dd < 16; ++dd) acc[dd] = 0.f;

  for (int jj = 0; jj < nj; ++jj) {
    const int j = jb + jj;
    float s = 0.f;
    for (int e = 0; e < 64; e += 4)
      s += dot4(*(const float4*)&Qs[r][e], *(const float4*)&Ks[j][e]);
    const float w = __expf(s - mm) * inv_ll;
    const float4* vrow = (const float4*)(V + j * 64 + dq * 16);
#pragma unroll
    for (int dd = 0; dd < 4; ++dd) {
      const float4 vv = vrow[dd];
      acc[dd * 4 + 0] += w * vv.x;
      acc[dd * 4 + 1] += w * vv.y;
      acc[dd * 4 + 2] += w * vv.z;
      acc[dd * 4 + 3] += w * vv.w;
    }
  }
  float* o = wv + (q0 + r) * CDIM + h * 64 + dq * 16;
#pragma unroll
  for (int dd = 0; dd < 16; ++dd) o[dd] = acc[dd];
}

// K4: y = (wv*dw_w + dw_b) @ pw_w^T + pw_b + x
// Tiled GEMM 64x64, BK=16, 4x4 per thread. Grid 64*8 = 512 blocks.
__global__ __launch_bounds__(256) void k_dyn(const float* __restrict__ wvp,
                                             const float* __restrict__ x,
                                             const float* __restrict__ dww,
                                             const float* __restrict__ dwb,
                                             const float* __restrict__ pww,
                                             const float* __restrict__ pwb,
                                             float* __restrict__ y) {
  __shared__ __align__(16) float As[16][68];  // [k][row]
  __shared__ __align__(16) float Ws[16][68];  // [k][col]
  const int rb = blockIdx.x >> 3;
  const int cb = blockIdx.x & 7;
  const int r0 = rb * 64, c0 = cb * 64;
  const int ty = threadIdx.x >> 4, tx = threadIdx.x & 15;
  const int lr = threadIdx.x >> 2;        // 0..63
  const int lk = (threadIdx.x & 3) << 2;  // 0,4,8,12
  float acc[4][4];
#pragma unroll
  for (int i = 0; i < 4; ++i)
#pragma unroll
    for (int j = 0; j < 4; ++j) acc[i][j] = 0.f;

  for (int k0 = 0; k0 < 512; k0 += 16) {
    // issue global loads before the barrier (overlap with previous compute)
    float4 a = *(const float4*)&wvp[(r0 + lr) * 512 + k0 + lk];
    const float4 dw4 = *(const float4*)&dww[k0 + lk];
    const float4 db4 = *(const float4*)&dwb[k0 + lk];
    a.x = a.x * dw4.x + db4.x;
    a.y = a.y * dw4.y + db4.y;
    a.z = a.z * dw4.z + db4.z;
    a.w = a.w * dw4.w + db4.w;
    const float4 w = *(const float4*)&pww[(c0 + lr) * 512 + k0 + lk];
    __syncthreads();
    As[lk + 0][lr] = a.x; As[lk + 1][lr] = a.y;
    As[lk + 2][lr] = a.z; As[lk + 3][lr] = a.w;
    Ws[lk + 0][lr] = w.x; Ws[lk + 1][lr] = w.y;
    Ws[lk + 2][lr] = w.z; Ws[lk + 3][lr] = w.w;
    __syncthreads();
#pragma unroll
    for (int k = 0; k < 16; ++k) {
      const float4 av = *(const float4*)&As[k][ty * 4];
      const float4 bv = *(const float4*)&Ws[k][tx * 4];
      const float ar[4] = {av.x, av.y, av.z, av.w};
      const float br[4] = {bv.x, bv.y, bv.z, bv.w};
#pragma unroll
      for (int i = 0; i < 4; ++i)
#pragma unroll
        for (int j = 0; j < 4; ++j) acc[i][j] += ar[i] * br[j];
    }
  }
  const int rr = r0 + ty * 4;
  const int cc = c0 + tx * 4;
  const float4 pb = *(const float4*)&pwb[cc];
#pragma unroll
  for (int i = 0; i < 4; ++i) {
    const float4 xv = *(const float4*)&x[(rr + i) * 512 + cc];
    float4 res;
    res.x = acc[i][0] + pb.x + xv.x;
    res.y = acc[i][1] + pb.y + xv.y;
    res.z = acc[i][2] + pb.z + xv.z;
    res.w = acc[i][3] + pb.w + xv.w;
    *(float4*)&y[(rr + i) * 512 + cc] = res;
  }
}

// K5a: tp[4096][32] = y @ p_w1^T. Tiled: BM=64, O=32, BK=16. Grid 64.
__global__ __launch_bounds__(256) void k_pout1(const float* __restrict__ y,
                                               const float* __restrict__ pw1,
                                               float* __restrict__ tp) {
  __shared__ __align__(16) float As[16][68];
  __shared__ __align__(16) float Ws[16][36];
  const int r0 = blockIdx.x * 64;
  const int ty = threadIdx.x >> 4, tx = threadIdx.x & 15;
  const int lr = threadIdx.x >> 2;
  const int lk = (threadIdx.x & 3) << 2;
  float acc[4][2];
#pragma unroll
  for (int i = 0; i < 4; ++i) { acc[i][0] = 0.f; acc[i][1] = 0.f; }

  for (int k0 = 0; k0 < 512; k0 += 16) {
    const float4 a = *(const float4*)&y[(r0 + lr) * 512 + k0 + lk];
    float4 w;
    const int wc = threadIdx.x >> 2;       // only threads < 128 valid (32 cols)
    if (threadIdx.x < 128) w = *(const float4*)&pw1[wc * 512 + k0 + lk];
    __syncthreads();
    As[lk + 0][lr] = a.x; As[lk + 1][lr] = a.y;
    As[lk + 2][lr] = a.z; As[lk + 3][lr] = a.w;
    if (threadIdx.x < 128) {
      Ws[lk + 0][wc] = w.x; Ws[lk + 1][wc] = w.y;
      Ws[lk + 2][wc] = w.z; Ws[lk + 3][wc] = w.w;
    }
    __syncthreads();
#pragma unroll
    for (int k = 0; k < 16; ++k) {
      const float4 av = *(const float4*)&As[k][ty * 4];
      const float ar[4] = {av.x, av.y, av.z, av.w};
      const float b0 = Ws[k][tx], b1 = Ws[k][tx + 16];
#pragma unroll
      for (int i = 0; i < 4; ++i) {
        acc[i][0] += ar[i] * b0;
        acc[i][1] += ar[i] * b1;
      }
    }
  }
#pragma unroll
  for (int i = 0; i < 4; ++i) {
    tp[(r0 + ty * 4 + i) * 32 + tx] = acc[i][0];
    tp[(r0 + ty * 4 + i) * 32 + tx + 16] = acc[i][1];
  }
}

// K5b: out[4096][512] = tp @ p_w2^T. Blocks: 64 rows x 16 cols. Grid 64*32.
__global__ __launch_bounds__(256) void k_pout2(const float* __restrict__ tp,
                                               const float* __restrict__ pw2,
                                               float* __restrict__ out) {
  __shared__ __align__(16) float ts[64][36];
  const int bc = blockIdx.x & 31;
  const int br = blockIdx.x >> 5;
  const int r0 = br * 64;
  for (int idx = threadIdx.x; idx < 512; idx += 256) {
    const int rr = idx >> 3;
    const int cc = (idx & 7) << 2;
    *(float4*)&ts[rr][cc] = *(const float4*)&tp[(r0 + rr) * 32 + cc];
  }
  __syncthreads();
  const int tx = threadIdx.x & 15, ty = threadIdx.x >> 4;
  const int c = bc * 16 + tx;
  const float* __restrict__ w = pw2 + c * 32;
  float4 wr[8];
#pragma unroll
  for (int e = 0; e < 8; ++e) wr[e] = *(const float4*)&w[e * 4];
#pragma unroll
  for (int i = 0; i < 4; ++i) {
    const int r = ty * 4 + i;
    float acc = 0.f;
#pragma unroll
    for (int e = 0; e < 8; ++e) acc += dot4(*(const float4*)&ts[r][e * 4], wr[e]);
    out[(r0 + r) * 512 + c] = acc;
  }
}

extern "C" void kernel_launch(void* const* d_in, const int* in_sizes, int n_in,
                              void* d_out, int out_size, void* d_ws, size_t ws_size,
                              hipStream_t stream) {
  const float* x     = (const float*)d_in[0];
  const float* q_w1  = (const float*)d_in[1];
  const float* q_w2  = (const float*)d_in[2];
  const float* kv_w1 = (const float*)d_in[3];
  const float* kv_w2 = (const float*)d_in[4];
  const float* dw_w  = (const float*)d_in[5];
  const float* dw_b  = (const float*)d_in[6];
  const float* pw_w  = (const float*)d_in[7];
  const float* pw_b  = (const float*)d_in[8];
  const float* p_w1  = (const float*)d_in[9];
  const float* p_w2  = (const float*)d_in[10];
  float* out = (float*)d_out;

  float* ws = (float*)d_ws;
  float* t  = ws;                         // 4096*96
  float* qh = t + NFULL * 96;             // 8*4096*64
  float* kh = qh + HEADS * NFULL * DDIM;
  float* vh = kh + HEADS * NFULL * DDIM;
  float* wv = vh + HEADS * NFULL * DDIM;  // 4096*512
  float* y  = wv + NFULL * CDIM;          // 4096*512
  float* tp = y + NFULL * CDIM;           // 4096*32

  k_proj1<<<NFULL / 64, 256, 0, stream>>>(x, q_w1, kv_w1, t);
  k_proj2<<<(NFULL / 64) * 96, 256, 0, stream>>>(t, q_w2, kv_w2, qh, kh, vh);
  k_attn<<<HEADS * (NFULL / 64), 256, 0, stream>>>(qh, kh, vh, wv);
  k_dyn<<<(NFULL / 64) * 8, 256, 0, stream>>>(wv, x, dw_w, dw_b, pw_w, pw_b, y);
  k_pout1<<<NFULL / 64, 256, 0, stream>>>(y, p_w1, tp);
  k_pout2<<<(NFULL / 64) * 32, 256, 0, stream>>>(tp, p_w2, out);
}

// Round 3
// 224.467 us; speedup vs baseline: 5.1338x; 2.5829x over previous
//
#include <hip/hip_runtime.h>

#define NFULL 4096
#define CDIM  512
#define HEADS 8
#define DDIM  64

typedef unsigned short u16;
typedef short bf16x8 __attribute__((ext_vector_type(8)));
typedef float f32x4 __attribute__((ext_vector_type(4)));

#if __has_builtin(__builtin_amdgcn_exp2f)
#define EXP2(x) __builtin_amdgcn_exp2f(x)
#else
#define EXP2(x) exp2f(x)
#endif

// q is pre-scaled by SCALE * log2(e) so softmax exp(s) == exp2(s').
#define QSCALE 11.541560327111707f  // 8 * 1.4426950408889634

__device__ __forceinline__ float dot4(float4 a, float4 b) {
  return a.x * b.x + a.y * b.y + a.z * b.z + a.w * b.w;
}

__device__ __forceinline__ u16 f2bf(float x) {  // RNE f32 -> bf16 bits
  union { float f; unsigned u; } v; v.f = x;
  unsigned r = v.u + 0x7fffu + ((v.u >> 16) & 1u);
  return (u16)(r >> 16);
}

// K1: t[4096][96] = x @ [q_w1; kv_w1]^T   (cols 0..31 = q_w1, 32..95 = kv_w1)
__global__ __launch_bounds__(256) void k_proj1(const float* __restrict__ x,
                                               const float* __restrict__ qw1,
                                               const float* __restrict__ kvw1,
                                               float* __restrict__ t) {
  __shared__ __align__(16) float As[16][68];   // [k][row]
  __shared__ __align__(16) float Ws[16][100];  // [k][col 0..95]
  const int r0 = blockIdx.x * 64;
  const int ty = threadIdx.x >> 4, tx = threadIdx.x & 15;
  const int lr = threadIdx.x >> 2;
  const int lk = (threadIdx.x & 3) << 2;
  float acc[4][6];
#pragma unroll
  for (int i = 0; i < 4; ++i)
#pragma unroll
    for (int j = 0; j < 6; ++j) acc[i][j] = 0.f;

  for (int k0 = 0; k0 < 512; k0 += 16) {
    __syncthreads();
    {
      const float4 a = *(const float4*)&x[(r0 + lr) * 512 + k0 + lk];
      As[lk + 0][lr] = a.x; As[lk + 1][lr] = a.y;
      As[lk + 2][lr] = a.z; As[lk + 3][lr] = a.w;
    }
    for (int idx = threadIdx.x; idx < 384; idx += 256) {
      const int c = idx >> 2;
      const int kk = (idx & 3) << 2;
      const float* __restrict__ wsrc = (c < 32) ? (qw1 + c * 512) : (kvw1 + (c - 32) * 512);
      const float4 w = *(const float4*)&wsrc[k0 + kk];
      Ws[kk + 0][c] = w.x; Ws[kk + 1][c] = w.y;
      Ws[kk + 2][c] = w.z; Ws[kk + 3][c] = w.w;
    }
    __syncthreads();
#pragma unroll
    for (int k = 0; k < 16; ++k) {
      const float4 a = *(const float4*)&As[k][ty * 4];
      const float ar[4] = {a.x, a.y, a.z, a.w};
      float br[6];
#pragma unroll
      for (int j = 0; j < 6; ++j) br[j] = Ws[k][tx + 16 * j];
#pragma unroll
      for (int i = 0; i < 4; ++i)
#pragma unroll
        for (int j = 0; j < 6; ++j) acc[i][j] += ar[i] * br[j];
    }
  }
#pragma unroll
  for (int i = 0; i < 4; ++i)
#pragma unroll
    for (int j = 0; j < 6; ++j)
      t[(r0 + ty * 4 + i) * 96 + tx + 16 * j] = acc[i][j];
}

// K2: qb = bf16(QSCALE * t_q @ q_w2^T); kb = bf16(t_kv @ kv_w2^T half 1);
//     vh = fp32 (t_kv @ kv_w2^T half 2). Layouts [H][N][D].
__global__ __launch_bounds__(256) void k_proj2(const float* __restrict__ t,
                                               const float* __restrict__ qw2,
                                               const float* __restrict__ kvw2,
                                               u16* __restrict__ qb,
                                               u16* __restrict__ kb,
                                               float* __restrict__ vh) {
  __shared__ __align__(16) float ts[64][100];
  const int bc = blockIdx.x % 96;
  const int br = blockIdx.x / 96;
  const int r0 = br * 64;
  for (int idx = threadIdx.x; idx < 1536; idx += 256) {
    const int rr = idx / 24;
    const int cc = (idx - rr * 24) * 4;
    *(float4*)&ts[rr][cc] = *(const float4*)&t[(r0 + rr) * 96 + cc];
  }
  __syncthreads();
  const int tx = threadIdx.x & 15, ty = threadIdx.x >> 4;
  const int c = bc * 16 + tx;
  if (c < 512) {
    const float* __restrict__ w = qw2 + c * 32;
    float4 wr[8];
#pragma unroll
    for (int e = 0; e < 8; ++e) wr[e] = *(const float4*)&w[e * 4];
    const int h = c >> 6, d = c & 63;
#pragma unroll
    for (int i = 0; i < 4; ++i) {
      const int r = ty * 4 + i;
      float acc = 0.f;
#pragma unroll
      for (int e = 0; e < 8; ++e) acc += dot4(*(const float4*)&ts[r][e * 4], wr[e]);
      qb[(h * NFULL + r0 + r) * 64 + d] = f2bf(acc * QSCALE);
    }
  } else {
    const int cc = c - 512;
    const float* __restrict__ w = kvw2 + cc * 64;
    float4 wr[16];
#pragma unroll
    for (int e = 0; e < 16; ++e) wr[e] = *(const float4*)&w[e * 4];
    const int c2 = cc & 511;
    const int h = c2 >> 6, d = c2 & 63;
#pragma unroll
    for (int i = 0; i < 4; ++i) {
      const int r = ty * 4 + i;
      float acc = 0.f;
#pragma unroll
      for (int e = 0; e < 16; ++e) acc += dot4(*(const float4*)&ts[r][32 + e * 4], wr[e]);
      if (cc < 512)
        kb[(h * NFULL + r0 + r) * 64 + d] = f2bf(acc);
      else
        vh[(h * NFULL + r0 + r) * 64 + d] = acc;
    }
  }
}

// K3: MFMA attention. Per block: head h, 64-query tile; 4 waves x 16 queries.
// Denominator: full-row sum of exp2(S) via mfma(K,Q) sweeps over all keys.
// Numerator: diagonal 16x16 subtile captured into P_lds during the sweep.
__global__ __launch_bounds__(256) void k_attn(const u16* __restrict__ qb,
                                              const u16* __restrict__ kb,
                                              const float* __restrict__ vh,
                                              float* __restrict__ wv) {
  __shared__ __align__(16) u16 Qs[64][72];
  __shared__ __align__(16) u16 Ks[2][64][72];
  __shared__ __align__(16) float Vs[64][68];
  __shared__ float P_lds[4][16][17];

  const int h = blockIdx.x >> 6;
  const int qt = blockIdx.x & 63;
  const int q0 = qt * 64;
  const int tid = threadIdx.x;
  const int wave = tid >> 6;
  const int lane = tid & 63;
  const int lrow = lane & 15;
  const int g = lane >> 4;

  const int srow = tid >> 2;          // staging: row 0..63
  const int scol = (tid & 3) * 16;    // staging: 16-elem chunk

  const u16* __restrict__ Qg = qb + (h * NFULL + q0) * 64;
  const u16* __restrict__ Kg = kb + h * NFULL * 64;
  const float* __restrict__ Vg = vh + (h * NFULL + q0) * 64;

  {  // prologue: stage Q (bf16), V rows of own tile (fp32), K tile 0 (bf16)
    const uint4* qsrc = (const uint4*)(Qg + srow * 64 + scol);
    const uint4 qa = qsrc[0], qb4 = qsrc[1];
    const float4* vsrc = (const float4*)(Vg + srow * 64 + scol);
    const float4 v0 = vsrc[0], v1 = vsrc[1], v2 = vsrc[2], v3 = vsrc[3];
    const uint4* ksrc = (const uint4*)(Kg + srow * 64 + scol);
    const uint4 ka = ksrc[0], kb4 = ksrc[1];
    *(uint4*)&Qs[srow][scol] = qa;
    *(uint4*)&Qs[srow][scol + 8] = qb4;
    *(float4*)&Vs[srow][scol + 0] = v0;
    *(float4*)&Vs[srow][scol + 4] = v1;
    *(float4*)&Vs[srow][scol + 8] = v2;
    *(float4*)&Vs[srow][scol + 12] = v3;
    *(uint4*)&Ks[0][srow][scol] = ka;
    *(uint4*)&Ks[0][srow][scol + 8] = kb4;
  }
  __syncthreads();

  // persistent Q B-fragments (col = lrow = query, k = g*8..+7 per 32-chunk)
  const bf16x8 qf0 = *(const bf16x8*)&Qs[wave * 16 + lrow][g * 8];
  const bf16x8 qf1 = *(const bf16x8*)&Qs[wave * 16 + lrow][32 + g * 8];

  float dsum = 0.f;
  const int diag = qt * 4 + wave;  // global 16-key subtile owned by this wave
  int cur = 0;

  for (int kt = 0; kt < 64; ++kt) {
    uint4 na, nb;
    if (kt + 1 < 64) {  // prefetch next K tile (hidden under MFMA+exp)
      const uint4* nsrc = (const uint4*)(Kg + ((kt + 1) * 64 + srow) * 64 + scol);
      na = nsrc[0]; nb = nsrc[1];
    }
#pragma unroll
    for (int sub = 0; sub < 4; ++sub) {
      const bf16x8 kf0 = *(const bf16x8*)&Ks[cur][sub * 16 + lrow][g * 8];
      const bf16x8 kf1 = *(const bf16x8*)&Ks[cur][sub * 16 + lrow][32 + g * 8];
      f32x4 acc = {0.f, 0.f, 0.f, 0.f};
      acc = __builtin_amdgcn_mfma_f32_16x16x32_bf16(kf0, qf0, acc, 0, 0, 0);
      acc = __builtin_amdgcn_mfma_f32_16x16x32_bf16(kf1, qf1, acc, 0, 0, 0);
      // D[key r][query c]: c = lane&15, r = g*4 + j
      const float e0 = EXP2(acc[0]);
      const float e1 = EXP2(acc[1]);
      const float e2 = EXP2(acc[2]);
      const float e3 = EXP2(acc[3]);
      dsum += (e0 + e1) + (e2 + e3);
      if (kt * 4 + sub == diag) {  // wave-uniform branch
        const int rr = g * 4;
        P_lds[wave][rr + 0][lrow] = (rr + 0 <= lrow) ? e0 : 0.f;
        P_lds[wave][rr + 1][lrow] = (rr + 1 <= lrow) ? e1 : 0.f;
        P_lds[wave][rr + 2][lrow] = (rr + 2 <= lrow) ? e2 : 0.f;
        P_lds[wave][rr + 3][lrow] = (rr + 3 <= lrow) ? e3 : 0.f;
      }
    }
    if (kt + 1 < 64) {
      *(uint4*)&Ks[cur ^ 1][srow][scol] = na;
      *(uint4*)&Ks[cur ^ 1][srow][scol + 8] = nb;
    }
    __syncthreads();
    cur ^= 1;
  }

  // full-row denominator: reduce the 4 key-row groups sharing each query col
  dsum += __shfl_xor(dsum, 16);
  dsum += __shfl_xor(dsum, 32);
  const float inv = 1.0f / dsum;

  // numerator: O[q][d] = sum_k P[k][q] * V[k][d], k in own 16-block
  float o[16];
#pragma unroll
  for (int dd = 0; dd < 16; ++dd) o[dd] = 0.f;
#pragma unroll
  for (int k = 0; k < 16; ++k) {
    const float p = P_lds[wave][k][lrow];
    const float4 v0 = *(const float4*)&Vs[wave * 16 + k][g * 16 + 0];
    const float4 v1 = *(const float4*)&Vs[wave * 16 + k][g * 16 + 4];
    const float4 v2 = *(const float4*)&Vs[wave * 16 + k][g * 16 + 8];
    const float4 v3 = *(const float4*)&Vs[wave * 16 + k][g * 16 + 12];
    o[0] += p * v0.x;  o[1] += p * v0.y;  o[2] += p * v0.z;  o[3] += p * v0.w;
    o[4] += p * v1.x;  o[5] += p * v1.y;  o[6] += p * v1.z;  o[7] += p * v1.w;
    o[8] += p * v2.x;  o[9] += p * v2.y;  o[10] += p * v2.z; o[11] += p * v2.w;
    o[12] += p * v3.x; o[13] += p * v3.y; o[14] += p * v3.z; o[15] += p * v3.w;
  }
  const int qglob = q0 + wave * 16 + lrow;
  float* __restrict__ op = wv + qglob * CDIM + h * 64 + g * 16;
#pragma unroll
  for (int c4 = 0; c4 < 4; ++c4) {
    float4 r;
    r.x = o[c4 * 4 + 0] * inv;
    r.y = o[c4 * 4 + 1] * inv;
    r.z = o[c4 * 4 + 2] * inv;
    r.w = o[c4 * 4 + 3] * inv;
    *(float4*)&op[c4 * 4] = r;
  }
}

// K4: y = (wv*dw_w + dw_b) @ pw_w^T + pw_b + x
__global__ __launch_bounds__(256) void k_dyn(const float* __restrict__ wvp,
                                             const float* __restrict__ x,
                                             const float* __restrict__ dww,
                                             const float* __restrict__ dwb,
                                             const float* __restrict__ pww,
                                             const float* __restrict__ pwb,
                                             float* __restrict__ y) {
  __shared__ __align__(16) float As[16][68];
  __shared__ __align__(16) float Ws[16][68];
  const int rb = blockIdx.x >> 3;
  const int cb = blockIdx.x & 7;
  const int r0 = rb * 64, c0 = cb * 64;
  const int ty = threadIdx.x >> 4, tx = threadIdx.x & 15;
  const int lr = threadIdx.x >> 2;
  const int lk = (threadIdx.x & 3) << 2;
  float acc[4][4];
#pragma unroll
  for (int i = 0; i < 4; ++i)
#pragma unroll
    for (int j = 0; j < 4; ++j) acc[i][j] = 0.f;

  for (int k0 = 0; k0 < 512; k0 += 16) {
    float4 a = *(const float4*)&wvp[(r0 + lr) * 512 + k0 + lk];
    const float4 dw4 = *(const float4*)&dww[k0 + lk];
    const float4 db4 = *(const float4*)&dwb[k0 + lk];
    a.x = a.x * dw4.x + db4.x;
    a.y = a.y * dw4.y + db4.y;
    a.z = a.z * dw4.z + db4.z;
    a.w = a.w * dw4.w + db4.w;
    const float4 w = *(const float4*)&pww[(c0 + lr) * 512 + k0 + lk];
    __syncthreads();
    As[lk + 0][lr] = a.x; As[lk + 1][lr] = a.y;
    As[lk + 2][lr] = a.z; As[lk + 3][lr] = a.w;
    Ws[lk + 0][lr] = w.x; Ws[lk + 1][lr] = w.y;
    Ws[lk + 2][lr] = w.z; Ws[lk + 3][lr] = w.w;
    __syncthreads();
#pragma unroll
    for (int k = 0; k < 16; ++k) {
      const float4 av = *(const float4*)&As[k][ty * 4];
      const float4 bv = *(const float4*)&Ws[k][tx * 4];
      const float ar[4] = {av.x, av.y, av.z, av.w};
      const float br[4] = {bv.x, bv.y, bv.z, bv.w};
#pragma unroll
      for (int i = 0; i < 4; ++i)
#pragma unroll
        for (int j = 0; j < 4; ++j) acc[i][j] += ar[i] * br[j];
    }
  }
  const int rr = r0 + ty * 4;
  const int cc = c0 + tx * 4;
  const float4 pb = *(const float4*)&pwb[cc];
#pragma unroll
  for (int i = 0; i < 4; ++i) {
    const float4 xv = *(const float4*)&x[(rr + i) * 512 + cc];
    float4 res;
    res.x = acc[i][0] + pb.x + xv.x;
    res.y = acc[i][1] + pb.y + xv.y;
    res.z = acc[i][2] + pb.z + xv.z;
    res.w = acc[i][3] + pb.w + xv.w;
    *(float4*)&y[(rr + i) * 512 + cc] = res;
  }
}

// K5a: tp[4096][32] = y @ p_w1^T
__global__ __launch_bounds__(256) void k_pout1(const float* __restrict__ y,
                                               const float* __restrict__ pw1,
                                               float* __restrict__ tp) {
  __shared__ __align__(16) float As[16][68];
  __shared__ __align__(16) float Ws[16][36];
  const int r0 = blockIdx.x * 64;
  const int ty = threadIdx.x >> 4, tx = threadIdx.x & 15;
  const int lr = threadIdx.x >> 2;
  const int lk = (threadIdx.x & 3) << 2;
  float acc[4][2];
#pragma unroll
  for (int i = 0; i < 4; ++i) { acc[i][0] = 0.f; acc[i][1] = 0.f; }

  for (int k0 = 0; k0 < 512; k0 += 16) {
    const float4 a = *(const float4*)&y[(r0 + lr) * 512 + k0 + lk];
    float4 w;
    const int wc = threadIdx.x >> 2;
    if (threadIdx.x < 128) w = *(const float4*)&pw1[wc * 512 + k0 + lk];
    __syncthreads();
    As[lk + 0][lr] = a.x; As[lk + 1][lr] = a.y;
    As[lk + 2][lr] = a.z; As[lk + 3][lr] = a.w;
    if (threadIdx.x < 128) {
      Ws[lk + 0][wc] = w.x; Ws[lk + 1][wc] = w.y;
      Ws[lk + 2][wc] = w.z; Ws[lk + 3][wc] = w.w;
    }
    __syncthreads();
#pragma unroll
    for (int k = 0; k < 16; ++k) {
      const float4 av = *(const float4*)&As[k][ty * 4];
      const float ar[4] = {av.x, av.y, av.z, av.w};
      const float b0 = Ws[k][tx], b1 = Ws[k][tx + 16];
#pragma unroll
      for (int i = 0; i < 4; ++i) {
        acc[i][0] += ar[i] * b0;
        acc[i][1] += ar[i] * b1;
      }
    }
  }
#pragma unroll
  for (int i = 0; i < 4; ++i) {
    tp[(r0 + ty * 4 + i) * 32 + tx] = acc[i][0];
    tp[(r0 + ty * 4 + i) * 32 + tx + 16] = acc[i][1];
  }
}

// K5b: out[4096][512] = tp @ p_w2^T
__global__ __launch_bounds__(256) void k_pout2(const float* __restrict__ tp,
                                               const float* __restrict__ pw2,
                                               float* __restrict__ out) {
  __shared__ __align__(16) float ts[64][36];
  const int bc = blockIdx.x & 31;
  const int br = blockIdx.x >> 5;
  const int r0 = br * 64;
  for (int idx = threadIdx.x; idx < 512; idx += 256) {
    const int rr = idx >> 3;
    const int cc = (idx & 7) << 2;
    *(float4*)&ts[rr][cc] = *(const float4*)&tp[(r0 + rr) * 32 + cc];
  }
  __syncthreads();
  const int tx = threadIdx.x & 15, ty = threadIdx.x >> 4;
  const int c = bc * 16 + tx;
  const float* __restrict__ w = pw2 + c * 32;
  float4 wr[8];
#pragma unroll
  for (int e = 0; e < 8; ++e) wr[e] = *(const float4*)&w[e * 4];
#pragma unroll
  for (int i = 0; i < 4; ++i) {
    const int r = ty * 4 + i;
    float acc = 0.f;
#pragma unroll
    for (int e = 0; e < 8; ++e) acc += dot4(*(const float4*)&ts[r][e * 4], wr[e]);
    out[(r0 + r) * 512 + c] = acc;
  }
}

extern "C" void kernel_launch(void* const* d_in, const int* in_sizes, int n_in,
                              void* d_out, int out_size, void* d_ws, size_t ws_size,
                              hipStream_t stream) {
  const float* x     = (const float*)d_in[0];
  const float* q_w1  = (const float*)d_in[1];
  const float* q_w2  = (const float*)d_in[2];
  const float* kv_w1 = (const float*)d_in[3];
  const float* kv_w2 = (const float*)d_in[4];
  const float* dw_w  = (const float*)d_in[5];
  const float* dw_b  = (const float*)d_in[6];
  const float* pw_w  = (const float*)d_in[7];
  const float* pw_b  = (const float*)d_in[8];
  const float* p_w1  = (const float*)d_in[9];
  const float* p_w2  = (const float*)d_in[10];
  float* out = (float*)d_out;

  char* ws = (char*)d_ws;
  float* t  = (float*)ws;                                   // 4096*96 f32
  u16*   qbw = (u16*)(ws + (size_t)NFULL * 96 * 4);         // H*N*64 bf16
  u16*   kbw = qbw + (size_t)HEADS * NFULL * DDIM;          // H*N*64 bf16
  float* vh = (float*)(ws + (size_t)NFULL * 96 * 4
                          + (size_t)2 * HEADS * NFULL * DDIM * 2);  // H*N*64 f32
  float* wv = vh + (size_t)HEADS * NFULL * DDIM;            // N*C f32
  float* y  = wv + (size_t)NFULL * CDIM;                    // N*C f32
  float* tp = y + (size_t)NFULL * CDIM;                     // N*32 f32

  k_proj1<<<NFULL / 64, 256, 0, stream>>>(x, q_w1, kv_w1, t);
  k_proj2<<<(NFULL / 64) * 96, 256, 0, stream>>>(t, q_w2, kv_w2, qbw, kbw, vh);
  k_attn<<<HEADS * (NFULL / 64), 256, 0, stream>>>(qbw, kbw, vh, wv);
  k_dyn<<<(NFULL / 64) * 8, 256, 0, stream>>>(wv, x, dw_w, dw_b, pw_w, pw_b, y);
  k_pout1<<<NFULL / 64, 256, 0, stream>>>(y, p_w1, tp);
  k_pout2<<<(NFULL / 64) * 32, 256, 0, stream>>>(tp, p_w2, out);
}

// Round 4
// 134.265 us; speedup vs baseline: 8.5828x; 1.6718x over previous
//
#include <hip/hip_runtime.h>

#define NFULL 4096
#define CDIM  512
#define HEADS 8
#define DDIM  64

typedef unsigned short u16;
typedef short bf16x8 __attribute__((ext_vector_type(8)));
typedef float f32x4 __attribute__((ext_vector_type(4)));

#if __has_builtin(__builtin_amdgcn_exp2f)
#define EXP2(x) __builtin_amdgcn_exp2f(x)
#else
#define EXP2(x) exp2f(x)
#endif

// q is pre-scaled by SCALE * log2(e) so softmax exp(s) == exp2(s').
#define QSCALE 11.541560327111707f  // 8 * 1.4426950408889634

__device__ __forceinline__ float dot4(float4 a, float4 b) {
  return a.x * b.x + a.y * b.y + a.z * b.z + a.w * b.w;
}

__device__ __forceinline__ u16 f2bf(float x) {  // RNE f32 -> bf16 bits
  union { float f; unsigned u; } v; v.f = x;
  unsigned r = v.u + 0x7fffu + ((v.u >> 16) & 1u);
  return (u16)(r >> 16);
}

// K1: t_part[ks][4096][96] = x @ [q_w1; kv_w1]^T over K chunk ks*128..+128.
// Grid 256 = 64 row-tiles x 4 K-splits.
__global__ __launch_bounds__(256) void k_proj1(const float* __restrict__ x,
                                               const float* __restrict__ qw1,
                                               const float* __restrict__ kvw1,
                                               float* __restrict__ t_part) {
  __shared__ __align__(16) float As[16][68];   // [k][row]
  __shared__ __align__(16) float Ws[16][100];  // [k][col 0..95]
  const int rb = blockIdx.x >> 2;
  const int ks = blockIdx.x & 3;
  const int r0 = rb * 64;
  const int ty = threadIdx.x >> 4, tx = threadIdx.x & 15;
  const int lr = threadIdx.x >> 2;
  const int lk = (threadIdx.x & 3) << 2;
  float acc[4][6];
#pragma unroll
  for (int i = 0; i < 4; ++i)
#pragma unroll
    for (int j = 0; j < 6; ++j) acc[i][j] = 0.f;

  for (int k0 = ks * 128; k0 < ks * 128 + 128; k0 += 16) {
    __syncthreads();
    {
      const float4 a = *(const float4*)&x[(r0 + lr) * 512 + k0 + lk];
      As[lk + 0][lr] = a.x; As[lk + 1][lr] = a.y;
      As[lk + 2][lr] = a.z; As[lk + 3][lr] = a.w;
    }
    for (int idx = threadIdx.x; idx < 384; idx += 256) {
      const int c = idx >> 2;
      const int kk = (idx & 3) << 2;
      const float* __restrict__ wsrc = (c < 32) ? (qw1 + c * 512) : (kvw1 + (c - 32) * 512);
      const float4 w = *(const float4*)&wsrc[k0 + kk];
      Ws[kk + 0][c] = w.x; Ws[kk + 1][c] = w.y;
      Ws[kk + 2][c] = w.z; Ws[kk + 3][c] = w.w;
    }
    __syncthreads();
#pragma unroll
    for (int k = 0; k < 16; ++k) {
      const float4 a = *(const float4*)&As[k][ty * 4];
      const float ar[4] = {a.x, a.y, a.z, a.w};
      float br[6];
#pragma unroll
      for (int j = 0; j < 6; ++j) br[j] = Ws[k][tx + 16 * j];
#pragma unroll
      for (int i = 0; i < 4; ++i)
#pragma unroll
        for (int j = 0; j < 6; ++j) acc[i][j] += ar[i] * br[j];
    }
  }
  float* __restrict__ tp = t_part + (size_t)ks * NFULL * 96;
#pragma unroll
  for (int i = 0; i < 4; ++i)
#pragma unroll
    for (int j = 0; j < 6; ++j)
      tp[(r0 + ty * 4 + i) * 96 + tx + 16 * j] = acc[i][j];
}

// K1b: t = sum of 4 partials (blocks 0..383); bias2[c] = dw_b @ pw_w[c,:] + pw_b[c]
// (blocks 384..385).
__global__ __launch_bounds__(256) void k_tred(const float* __restrict__ t_part,
                                              float* __restrict__ t,
                                              const float* __restrict__ pww,
                                              const float* __restrict__ dwb,
                                              const float* __restrict__ pwb,
                                              float* __restrict__ bias2) {
  const int b = blockIdx.x;
  if (b < 384) {
    const int i = b * 256 + threadIdx.x;  // float4 index, 98304 total
    const float4* __restrict__ src = (const float4*)t_part;
    float4 s = src[i];
#pragma unroll
    for (int p = 1; p < 4; ++p) {
      const float4 v = src[(size_t)p * 98304 + i];
      s.x += v.x; s.y += v.y; s.z += v.z; s.w += v.w;
    }
    ((float4*)t)[i] = s;
  } else {
    const int c = (b - 384) * 256 + threadIdx.x;  // 0..511
    float acc = 0.f;
    for (int e = 0; e < 512; e += 4)
      acc += dot4(*(const float4*)&pww[c * 512 + e], *(const float4*)&dwb[e]);
    bias2[c] = acc + pwb[c];
  }
}

// K2: qb = bf16(QSCALE * t_q @ q_w2^T); kb = bf16(kv half 1); vh = f32 (half 2).
// Weights staged in LDS (kills 16x redundant L2 reads).
__global__ __launch_bounds__(256) void k_proj2(const float* __restrict__ t,
                                               const float* __restrict__ qw2,
                                               const float* __restrict__ kvw2,
                                               u16* __restrict__ qb,
                                               u16* __restrict__ kb,
                                               float* __restrict__ vh) {
  __shared__ __align__(16) float ts[64][100];
  __shared__ __align__(16) float Wl[16][68];
  const int bc = blockIdx.x % 96;
  const int br = blockIdx.x / 96;
  const int r0 = br * 64;
  for (int idx = threadIdx.x; idx < 1536; idx += 256) {
    const int rr = idx / 24;
    const int cc = (idx - rr * 24) * 4;
    *(float4*)&ts[rr][cc] = *(const float4*)&t[(r0 + rr) * 96 + cc];
  }
  const int cbase = bc * 16;
  if (cbase < 512) {  // q half: 16 cols x 32 K
    if (threadIdx.x < 128) {
      const int col = threadIdx.x >> 3;
      const int ko = (threadIdx.x & 7) * 4;
      *(float4*)&Wl[col][ko] = *(const float4*)&qw2[(cbase + col) * 32 + ko];
    }
  } else {            // kv half: 16 cols x 64 K
    const int col = threadIdx.x >> 4;
    const int ko = (threadIdx.x & 15) * 4;
    *(float4*)&Wl[col][ko] = *(const float4*)&kvw2[(cbase - 512 + col) * 64 + ko];
  }
  __syncthreads();
  const int tx = threadIdx.x & 15, ty = threadIdx.x >> 4;
  const int c = cbase + tx;
  if (c < 512) {
    float4 wr[8];
#pragma unroll
    for (int e = 0; e < 8; ++e) wr[e] = *(const float4*)&Wl[tx][e * 4];
    const int h = c >> 6, d = c & 63;
#pragma unroll
    for (int i = 0; i < 4; ++i) {
      const int r = ty * 4 + i;
      float acc = 0.f;
#pragma unroll
      for (int e = 0; e < 8; ++e) acc += dot4(*(const float4*)&ts[r][e * 4], wr[e]);
      qb[(h * NFULL + r0 + r) * 64 + d] = f2bf(acc * QSCALE);
    }
  } else {
    float4 wr[16];
#pragma unroll
    for (int e = 0; e < 16; ++e) wr[e] = *(const float4*)&Wl[tx][e * 4];
    const int cc = c - 512;
    const int c2 = cc & 511;
    const int h = c2 >> 6, d = c2 & 63;
#pragma unroll
    for (int i = 0; i < 4; ++i) {
      const int r = ty * 4 + i;
      float acc = 0.f;
#pragma unroll
      for (int e = 0; e < 16; ++e) acc += dot4(*(const float4*)&ts[r][32 + e * 4], wr[e]);
      if (cc < 512)
        kb[(h * NFULL + r0 + r) * 64 + d] = f2bf(acc);
      else
        vh[(h * NFULL + r0 + r) * 64 + d] = acc;
    }
  }
}

// K3: MFMA attention; wv output now bf16 [N][C].
__global__ __launch_bounds__(256) void k_attn(const u16* __restrict__ qb,
                                              const u16* __restrict__ kb,
                                              const float* __restrict__ vh,
                                              u16* __restrict__ wv) {
  __shared__ __align__(16) u16 Qs[64][72];
  __shared__ __align__(16) u16 Ks[2][64][72];
  __shared__ __align__(16) float Vs[64][68];
  __shared__ float P_lds[4][16][17];

  const int h = blockIdx.x >> 6;
  const int qt = blockIdx.x & 63;
  const int q0 = qt * 64;
  const int tid = threadIdx.x;
  const int wave = tid >> 6;
  const int lane = tid & 63;
  const int lrow = lane & 15;
  const int g = lane >> 4;

  const int srow = tid >> 2;
  const int scol = (tid & 3) * 16;

  const u16* __restrict__ Qg = qb + (h * NFULL + q0) * 64;
  const u16* __restrict__ Kg = kb + h * NFULL * 64;
  const float* __restrict__ Vg = vh + (h * NFULL + q0) * 64;

  {
    const uint4* qsrc = (const uint4*)(Qg + srow * 64 + scol);
    const uint4 qa = qsrc[0], qb4 = qsrc[1];
    const float4* vsrc = (const float4*)(Vg + srow * 64 + scol);
    const float4 v0 = vsrc[0], v1 = vsrc[1], v2 = vsrc[2], v3 = vsrc[3];
    const uint4* ksrc = (const uint4*)(Kg + srow * 64 + scol);
    const uint4 ka = ksrc[0], kb4 = ksrc[1];
    *(uint4*)&Qs[srow][scol] = qa;
    *(uint4*)&Qs[srow][scol + 8] = qb4;
    *(float4*)&Vs[srow][scol + 0] = v0;
    *(float4*)&Vs[srow][scol + 4] = v1;
    *(float4*)&Vs[srow][scol + 8] = v2;
    *(float4*)&Vs[srow][scol + 12] = v3;
    *(uint4*)&Ks[0][srow][scol] = ka;
    *(uint4*)&Ks[0][srow][scol + 8] = kb4;
  }
  __syncthreads();

  const bf16x8 qf0 = *(const bf16x8*)&Qs[wave * 16 + lrow][g * 8];
  const bf16x8 qf1 = *(const bf16x8*)&Qs[wave * 16 + lrow][32 + g * 8];

  float dsum = 0.f;
  const int diag = qt * 4 + wave;
  int cur = 0;

  for (int kt = 0; kt < 64; ++kt) {
    uint4 na, nb;
    if (kt + 1 < 64) {
      const uint4* nsrc = (const uint4*)(Kg + ((kt + 1) * 64 + srow) * 64 + scol);
      na = nsrc[0]; nb = nsrc[1];
    }
#pragma unroll
    for (int sub = 0; sub < 4; ++sub) {
      const bf16x8 kf0 = *(const bf16x8*)&Ks[cur][sub * 16 + lrow][g * 8];
      const bf16x8 kf1 = *(const bf16x8*)&Ks[cur][sub * 16 + lrow][32 + g * 8];
      f32x4 acc = {0.f, 0.f, 0.f, 0.f};
      acc = __builtin_amdgcn_mfma_f32_16x16x32_bf16(kf0, qf0, acc, 0, 0, 0);
      acc = __builtin_amdgcn_mfma_f32_16x16x32_bf16(kf1, qf1, acc, 0, 0, 0);
      const float e0 = EXP2(acc[0]);
      const float e1 = EXP2(acc[1]);
      const float e2 = EXP2(acc[2]);
      const float e3 = EXP2(acc[3]);
      dsum += (e0 + e1) + (e2 + e3);
      if (kt * 4 + sub == diag) {
        const int rr = g * 4;
        P_lds[wave][rr + 0][lrow] = (rr + 0 <= lrow) ? e0 : 0.f;
        P_lds[wave][rr + 1][lrow] = (rr + 1 <= lrow) ? e1 : 0.f;
        P_lds[wave][rr + 2][lrow] = (rr + 2 <= lrow) ? e2 : 0.f;
        P_lds[wave][rr + 3][lrow] = (rr + 3 <= lrow) ? e3 : 0.f;
      }
    }
    if (kt + 1 < 64) {
      *(uint4*)&Ks[cur ^ 1][srow][scol] = na;
      *(uint4*)&Ks[cur ^ 1][srow][scol + 8] = nb;
    }
    __syncthreads();
    cur ^= 1;
  }

  dsum += __shfl_xor(dsum, 16);
  dsum += __shfl_xor(dsum, 32);
  const float inv = 1.0f / dsum;

  float o[16];
#pragma unroll
  for (int dd = 0; dd < 16; ++dd) o[dd] = 0.f;
#pragma unroll
  for (int k = 0; k < 16; ++k) {
    const float p = P_lds[wave][k][lrow];
    const float4 v0 = *(const float4*)&Vs[wave * 16 + k][g * 16 + 0];
    const float4 v1 = *(const float4*)&Vs[wave * 16 + k][g * 16 + 4];
    const float4 v2 = *(const float4*)&Vs[wave * 16 + k][g * 16 + 8];
    const float4 v3 = *(const float4*)&Vs[wave * 16 + k][g * 16 + 12];
    o[0] += p * v0.x;  o[1] += p * v0.y;  o[2] += p * v0.z;  o[3] += p * v0.w;
    o[4] += p * v1.x;  o[5] += p * v1.y;  o[6] += p * v1.z;  o[7] += p * v1.w;
    o[8] += p * v2.x;  o[9] += p * v2.y;  o[10] += p * v2.z; o[11] += p * v2.w;
    o[12] += p * v3.x; o[13] += p * v3.y; o[14] += p * v3.z; o[15] += p * v3.w;
  }
  u16 ob[16];
#pragma unroll
  for (int dd = 0; dd < 16; ++dd) ob[dd] = f2bf(o[dd] * inv);
  const int qglob = q0 + wave * 16 + lrow;
  u16* __restrict__ op = wv + (size_t)qglob * CDIM + h * 64 + g * 16;
  *(uint4*)&op[0] = *(const uint4*)&ob[0];
  *(uint4*)&op[8] = *(const uint4*)&ob[8];
}

// K4: y = wv @ (pw_w * dw_w)^T + bias2 + x, bf16 MFMA. Grid 64x8 = 512.
__global__ __launch_bounds__(256) void k_dyn(const u16* __restrict__ wv,
                                             const float* __restrict__ x,
                                             const float* __restrict__ dww,
                                             const float* __restrict__ pww,
                                             const float* __restrict__ bias2,
                                             float* __restrict__ y) {
  __shared__ __align__(16) u16 Ab[64][72];
  __shared__ __align__(16) u16 Wb[64][72];
  __shared__ __align__(16) float dwl[512];
  const int rb = blockIdx.x >> 3, cb = blockIdx.x & 7;
  const int r0 = rb * 64, c0 = cb * 64;
  const int tid = threadIdx.x;
  const int wave = tid >> 6, lane = tid & 63;
  const int lrow = lane & 15, g = lane >> 4;
  const int srow = tid >> 2;
  const int skc = (tid & 3) * 16;

  *(float2*)&dwl[tid * 2] = *(const float2*)&dww[tid * 2];

  f32x4 acc[4];
#pragma unroll
  for (int ct = 0; ct < 4; ++ct) acc[ct] = (f32x4){0.f, 0.f, 0.f, 0.f};
  __syncthreads();  // dwl ready

  for (int k0 = 0; k0 < 512; k0 += 64) {
    const u16* ap = wv + (size_t)(r0 + srow) * 512 + k0 + skc;
    const uint4 a0 = *(const uint4*)ap;
    const uint4 a1 = *(const uint4*)(ap + 8);
    const float* wp = pww + (size_t)(c0 + srow) * 512 + k0 + skc;
    float4 w4[4];
#pragma unroll
    for (int e = 0; e < 4; ++e) w4[e] = *(const float4*)&wp[e * 4];
    float4 d4[4];
#pragma unroll
    for (int e = 0; e < 4; ++e) d4[e] = *(const float4*)&dwl[k0 + skc + e * 4];
    u16 wb16[16];
#pragma unroll
    for (int e = 0; e < 4; ++e) {
      wb16[e * 4 + 0] = f2bf(w4[e].x * d4[e].x);
      wb16[e * 4 + 1] = f2bf(w4[e].y * d4[e].y);
      wb16[e * 4 + 2] = f2bf(w4[e].z * d4[e].z);
      wb16[e * 4 + 3] = f2bf(w4[e].w * d4[e].w);
    }
    __syncthreads();
    *(uint4*)&Ab[srow][skc] = a0;
    *(uint4*)&Ab[srow][skc + 8] = a1;
    *(uint4*)&Wb[srow][skc] = *(const uint4*)&wb16[0];
    *(uint4*)&Wb[srow][skc + 8] = *(const uint4*)&wb16[8];
    __syncthreads();
#pragma unroll
    for (int kk = 0; kk < 2; ++kk) {
      const bf16x8 af = *(const bf16x8*)&Ab[wave * 16 + lrow][kk * 32 + g * 8];
#pragma unroll
      for (int ct = 0; ct < 4; ++ct) {
        const bf16x8 wf = *(const bf16x8*)&Wb[ct * 16 + lrow][kk * 32 + g * 8];
        acc[ct] = __builtin_amdgcn_mfma_f32_16x16x32_bf16(wf, af, acc[ct], 0, 0, 0);
      }
    }
  }
  const int row = r0 + wave * 16 + lrow;
#pragma unroll
  for (int ct = 0; ct < 4; ++ct) {
    const int c = c0 + ct * 16 + g * 4;
    const float4 bb = *(const float4*)&bias2[c];
    const float4 xv = *(const float4*)&x[(size_t)row * 512 + c];
    float4 res;
    res.x = acc[ct][0] + bb.x + xv.x;
    res.y = acc[ct][1] + bb.y + xv.y;
    res.z = acc[ct][2] + bb.z + xv.z;
    res.w = acc[ct][3] + bb.w + xv.w;
    *(float4*)&y[(size_t)row * 512 + c] = res;
  }
}

// K5a: tp_part[ks][4096][32] = y @ p_w1^T over K chunk. Grid 64x4 = 256.
__global__ __launch_bounds__(256) void k_pout1(const float* __restrict__ y,
                                               const float* __restrict__ pw1,
                                               float* __restrict__ tp_part) {
  __shared__ __align__(16) float As[16][68];
  __shared__ __align__(16) float Ws[16][36];
  const int rb = blockIdx.x >> 2;
  const int ks = blockIdx.x & 3;
  const int r0 = rb * 64;
  const int ty = threadIdx.x >> 4, tx = threadIdx.x & 15;
  const int lr = threadIdx.x >> 2;
  const int lk = (threadIdx.x & 3) << 2;
  float acc[4][2];
#pragma unroll
  for (int i = 0; i < 4; ++i) { acc[i][0] = 0.f; acc[i][1] = 0.f; }

  for (int k0 = ks * 128; k0 < ks * 128 + 128; k0 += 16) {
    const float4 a = *(const float4*)&y[(r0 + lr) * 512 + k0 + lk];
    float4 w;
    const int wc = threadIdx.x >> 2;
    if (threadIdx.x < 128) w = *(const float4*)&pw1[wc * 512 + k0 + lk];
    __syncthreads();
    As[lk + 0][lr] = a.x; As[lk + 1][lr] = a.y;
    As[lk + 2][lr] = a.z; As[lk + 3][lr] = a.w;
    if (threadIdx.x < 128) {
      Ws[lk + 0][wc] = w.x; Ws[lk + 1][wc] = w.y;
      Ws[lk + 2][wc] = w.z; Ws[lk + 3][wc] = w.w;
    }
    __syncthreads();
#pragma unroll
    for (int k = 0; k < 16; ++k) {
      const float4 av = *(const float4*)&As[k][ty * 4];
      const float ar[4] = {av.x, av.y, av.z, av.w};
      const float b0 = Ws[k][tx], b1 = Ws[k][tx + 16];
#pragma unroll
      for (int i = 0; i < 4; ++i) {
        acc[i][0] += ar[i] * b0;
        acc[i][1] += ar[i] * b1;
      }
    }
  }
  float* __restrict__ tp = tp_part + (size_t)ks * NFULL * 32;
#pragma unroll
  for (int i = 0; i < 4; ++i) {
    tp[(r0 + ty * 4 + i) * 32 + tx] = acc[i][0];
    tp[(r0 + ty * 4 + i) * 32 + tx + 16] = acc[i][1];
  }
}

// K5b: out = (sum of tp partials) @ p_w2^T. Grid 64x32 = 2048.
__global__ __launch_bounds__(256) void k_pout2(const float* __restrict__ tp_part,
                                               const float* __restrict__ pw2,
                                               float* __restrict__ out) {
  __shared__ __align__(16) float ts[64][36];
  const int bc = blockIdx.x & 31;
  const int br = blockIdx.x >> 5;
  const int r0 = br * 64;
  for (int idx = threadIdx.x; idx < 512; idx += 256) {
    const int rr = idx >> 3;
    const int cc = (idx & 7) << 2;
    float4 s = {0.f, 0.f, 0.f, 0.f};
#pragma unroll
    for (int p = 0; p < 4; ++p) {
      const float4 v = *(const float4*)&tp_part[((size_t)p * NFULL + r0 + rr) * 32 + cc];
      s.x += v.x; s.y += v.y; s.z += v.z; s.w += v.w;
    }
    *(float4*)&ts[rr][cc] = s;
  }
  __syncthreads();
  const int tx = threadIdx.x & 15, ty = threadIdx.x >> 4;
  const int c = bc * 16 + tx;
  const float* __restrict__ w = pw2 + c * 32;
  float4 wr[8];
#pragma unroll
  for (int e = 0; e < 8; ++e) wr[e] = *(const float4*)&w[e * 4];
#pragma unroll
  for (int i = 0; i < 4; ++i) {
    const int r = ty * 4 + i;
    float acc = 0.f;
#pragma unroll
    for (int e = 0; e < 8; ++e) acc += dot4(*(const float4*)&ts[r][e * 4], wr[e]);
    out[(r0 + r) * 512 + c] = acc;
  }
}

extern "C" void kernel_launch(void* const* d_in, const int* in_sizes, int n_in,
                              void* d_out, int out_size, void* d_ws, size_t ws_size,
                              hipStream_t stream) {
  const float* x     = (const float*)d_in[0];
  const float* q_w1  = (const float*)d_in[1];
  const float* q_w2  = (const float*)d_in[2];
  const float* kv_w1 = (const float*)d_in[3];
  const float* kv_w2 = (const float*)d_in[4];
  const float* dw_w  = (const float*)d_in[5];
  const float* dw_b  = (const float*)d_in[6];
  const float* pw_w  = (const float*)d_in[7];
  const float* pw_b  = (const float*)d_in[8];
  const float* p_w1  = (const float*)d_in[9];
  const float* p_w2  = (const float*)d_in[10];
  float* out = (float*)d_out;

  char* ws = (char*)d_ws;
  float* t     = (float*)ws;                                  // 4096*96 f32 (1.57MB)
  float* bias2 = t + NFULL * 96;                              // 1024 f32 pad
  u16*   qbw   = (u16*)(bias2 + 1024);                        // 2M u16 (4MB)
  u16*   kbw   = qbw + (size_t)HEADS * NFULL * DDIM;          // 2M u16 (4MB)
  float* vh    = (float*)(kbw + (size_t)HEADS * NFULL * DDIM);// 2M f32 (8MB)
  u16*   wv16  = (u16*)(vh + (size_t)HEADS * NFULL * DDIM);   // 2M u16 (4MB)
  float* y     = (float*)(wv16 + (size_t)NFULL * CDIM);       // 2M f32 (8MB)
  float* t_part = y;   // alias: t_part (6.3MB) consumed by k_tred before y written
  float* tp_part = y + (size_t)NFULL * CDIM;                  // 4*4096*32 f32 (2MB)

  k_proj1<<<256, 256, 0, stream>>>(x, q_w1, kv_w1, t_part);
  k_tred<<<386, 256, 0, stream>>>(t_part, t, pw_w, dw_b, pw_b, bias2);
  k_proj2<<<(NFULL / 64) * 96, 256, 0, stream>>>(t, q_w2, kv_w2, qbw, kbw, vh);
  k_attn<<<HEADS * (NFULL / 64), 256, 0, stream>>>(qbw, kbw, vh, wv16);
  k_dyn<<<(NFULL / 64) * 8, 256, 0, stream>>>(wv16, x, dw_w, pw_w, bias2, y);
  k_pout1<<<256, 256, 0, stream>>>(y, p_w1, tp_part);
  k_pout2<<<(NFULL / 64) * 32, 256, 0, stream>>>(tp_part, p_w2, out);
}

// Round 5
// 125.203 us; speedup vs baseline: 9.2039x; 1.0724x over previous
//
#include <hip/hip_runtime.h>

#define NFULL 4096
#define CDIM  512
#define HEADS 8
#define DDIM  64

typedef unsigned short u16;
typedef short bf16x8 __attribute__((ext_vector_type(8)));
typedef float f32x4 __attribute__((ext_vector_type(4)));

#if __has_builtin(__builtin_amdgcn_exp2f)
#define EXP2(x) __builtin_amdgcn_exp2f(x)
#else
#define EXP2(x) exp2f(x)
#endif

// q is pre-scaled by SCALE * log2(e) so softmax exp(s) == exp2(s').
#define QSCALE 11.541560327111707f  // 8 * 1.4426950408889634

__device__ __forceinline__ float dot4(float4 a, float4 b) {
  return a.x * b.x + a.y * b.y + a.z * b.z + a.w * b.w;
}

__device__ __forceinline__ u16 f2bf(float x) {  // RNE f32 -> bf16 bits
  union { float f; unsigned u; } v; v.f = x;
  unsigned r = v.u + 0x7fffu + ((v.u >> 16) & 1u);
  return (u16)(r >> 16);
}

// K1: t_part[ks][4096][96] = x @ [q_w1; kv_w1]^T over K chunk ks*64..+64.
// Grid 512 = 64 row-tiles x 8 K-splits.
__global__ __launch_bounds__(256) void k_proj1(const float* __restrict__ x,
                                               const float* __restrict__ qw1,
                                               const float* __restrict__ kvw1,
                                               float* __restrict__ t_part) {
  __shared__ __align__(16) float As[16][68];   // [k][row]
  __shared__ __align__(16) float Ws[16][100];  // [k][col 0..95]
  const int rb = blockIdx.x >> 3;
  const int ks = blockIdx.x & 7;
  const int r0 = rb * 64;
  const int ty = threadIdx.x >> 4, tx = threadIdx.x & 15;
  const int lr = threadIdx.x >> 2;
  const int lk = (threadIdx.x & 3) << 2;
  float acc[4][6];
#pragma unroll
  for (int i = 0; i < 4; ++i)
#pragma unroll
    for (int j = 0; j < 6; ++j) acc[i][j] = 0.f;

  for (int k0 = ks * 64; k0 < ks * 64 + 64; k0 += 16) {
    __syncthreads();
    {
      const float4 a = *(const float4*)&x[(r0 + lr) * 512 + k0 + lk];
      As[lk + 0][lr] = a.x; As[lk + 1][lr] = a.y;
      As[lk + 2][lr] = a.z; As[lk + 3][lr] = a.w;
    }
    for (int idx = threadIdx.x; idx < 384; idx += 256) {
      const int c = idx >> 2;
      const int kk = (idx & 3) << 2;
      const float* __restrict__ wsrc = (c < 32) ? (qw1 + c * 512) : (kvw1 + (c - 32) * 512);
      const float4 w = *(const float4*)&wsrc[k0 + kk];
      Ws[kk + 0][c] = w.x; Ws[kk + 1][c] = w.y;
      Ws[kk + 2][c] = w.z; Ws[kk + 3][c] = w.w;
    }
    __syncthreads();
#pragma unroll
    for (int k = 0; k < 16; ++k) {
      const float4 a = *(const float4*)&As[k][ty * 4];
      const float ar[4] = {a.x, a.y, a.z, a.w};
      float br[6];
#pragma unroll
      for (int j = 0; j < 6; ++j) br[j] = Ws[k][tx + 16 * j];
#pragma unroll
      for (int i = 0; i < 4; ++i)
#pragma unroll
        for (int j = 0; j < 6; ++j) acc[i][j] += ar[i] * br[j];
    }
  }
  float* __restrict__ tp = t_part + (size_t)ks * NFULL * 96;
#pragma unroll
  for (int i = 0; i < 4; ++i)
#pragma unroll
    for (int j = 0; j < 6; ++j)
      tp[(r0 + ty * 4 + i) * 96 + tx + 16 * j] = acc[i][j];
}

// K1b: blocks 0..383: t = sum of 8 partials. Blocks 384..385: bias2 = dw_b@pw_w^T+pw_b.
// Blocks 386..449: pwbf[c][k] = bf16(pw_w[c][k] * dw_w[k]).
__global__ __launch_bounds__(256) void k_tred(const float* __restrict__ t_part,
                                              float* __restrict__ t,
                                              const float* __restrict__ pww,
                                              const float* __restrict__ dww,
                                              const float* __restrict__ dwb,
                                              const float* __restrict__ pwb,
                                              float* __restrict__ bias2,
                                              u16* __restrict__ pwbf) {
  const int b = blockIdx.x;
  if (b < 384) {
    const int i = b * 256 + threadIdx.x;  // float4 index, 98304 total
    const float4* __restrict__ src = (const float4*)t_part;
    float4 s = src[i];
#pragma unroll
    for (int p = 1; p < 8; ++p) {
      const float4 v = src[(size_t)p * 98304 + i];
      s.x += v.x; s.y += v.y; s.z += v.z; s.w += v.w;
    }
    ((float4*)t)[i] = s;
  } else if (b < 386) {
    const int c = (b - 384) * 256 + threadIdx.x;  // 0..511
    float acc = 0.f;
    for (int e = 0; e < 512; e += 4)
      acc += dot4(*(const float4*)&pww[c * 512 + e], *(const float4*)&dwb[e]);
    bias2[c] = acc + pwb[c];
  } else {
    const int base = (b - 386) * 4096 + threadIdx.x * 16;  // 16 elems/thread
    const int e0 = base & 511;
    u16 o[16];
#pragma unroll
    for (int q = 0; q < 4; ++q) {
      const float4 w = *(const float4*)&pww[base + q * 4];
      const float4 d = *(const float4*)&dww[e0 + q * 4];
      o[q * 4 + 0] = f2bf(w.x * d.x);
      o[q * 4 + 1] = f2bf(w.y * d.y);
      o[q * 4 + 2] = f2bf(w.z * d.z);
      o[q * 4 + 3] = f2bf(w.w * d.w);
    }
    *(uint4*)&pwbf[base] = *(const uint4*)&o[0];
    *(uint4*)&pwbf[base + 8] = *(const uint4*)&o[8];
  }
}

// K2: qb = bf16(QSCALE * t_q @ q_w2^T); kb = bf16(kv half 1); vh = f32 (half 2).
__global__ __launch_bounds__(256) void k_proj2(const float* __restrict__ t,
                                               const float* __restrict__ qw2,
                                               const float* __restrict__ kvw2,
                                               u16* __restrict__ qb,
                                               u16* __restrict__ kb,
                                               float* __restrict__ vh) {
  __shared__ __align__(16) float ts[64][100];
  __shared__ __align__(16) float Wl[16][68];
  const int bc = blockIdx.x % 96;
  const int br = blockIdx.x / 96;
  const int r0 = br * 64;
  for (int idx = threadIdx.x; idx < 1536; idx += 256) {
    const int rr = idx / 24;
    const int cc = (idx - rr * 24) * 4;
    *(float4*)&ts[rr][cc] = *(const float4*)&t[(r0 + rr) * 96 + cc];
  }
  const int cbase = bc * 16;
  if (cbase < 512) {
    if (threadIdx.x < 128) {
      const int col = threadIdx.x >> 3;
      const int ko = (threadIdx.x & 7) * 4;
      *(float4*)&Wl[col][ko] = *(const float4*)&qw2[(cbase + col) * 32 + ko];
    }
  } else {
    const int col = threadIdx.x >> 4;
    const int ko = (threadIdx.x & 15) * 4;
    *(float4*)&Wl[col][ko] = *(const float4*)&kvw2[(cbase - 512 + col) * 64 + ko];
  }
  __syncthreads();
  const int tx = threadIdx.x & 15, ty = threadIdx.x >> 4;
  const int c = cbase + tx;
  if (c < 512) {
    float4 wr[8];
#pragma unroll
    for (int e = 0; e < 8; ++e) wr[e] = *(const float4*)&Wl[tx][e * 4];
    const int h = c >> 6, d = c & 63;
#pragma unroll
    for (int i = 0; i < 4; ++i) {
      const int r = ty * 4 + i;
      float acc = 0.f;
#pragma unroll
      for (int e = 0; e < 8; ++e) acc += dot4(*(const float4*)&ts[r][e * 4], wr[e]);
      qb[(h * NFULL + r0 + r) * 64 + d] = f2bf(acc * QSCALE);
    }
  } else {
    float4 wr[16];
#pragma unroll
    for (int e = 0; e < 16; ++e) wr[e] = *(const float4*)&Wl[tx][e * 4];
    const int cc = c - 512;
    const int c2 = cc & 511;
    const int h = c2 >> 6, d = c2 & 63;
#pragma unroll
    for (int i = 0; i < 4; ++i) {
      const int r = ty * 4 + i;
      float acc = 0.f;
#pragma unroll
      for (int e = 0; e < 16; ++e) acc += dot4(*(const float4*)&ts[r][32 + e * 4], wr[e]);
      if (cc < 512)
        kb[(h * NFULL + r0 + r) * 64 + d] = f2bf(acc);
      else
        vh[(h * NFULL + r0 + r) * 64 + d] = acc;
    }
  }
}

// K3: LDS-free MFMA attention. Each wave owns key-group kt*4+wave, holds all
// 4 Q-fragments in registers; K fragments read directly from global (L2-hot).
// h = bid&7 so each XCD's L2 caches one head's K/V.
__global__ __launch_bounds__(256) void k_attn(const u16* __restrict__ qb,
                                              const u16* __restrict__ kb,
                                              const float* __restrict__ vh,
                                              u16* __restrict__ wv) {
  __shared__ float P_lds[4][16][17];
  __shared__ float Ds[4][4][16];
  const int h = blockIdx.x & 7;
  const int qt = blockIdx.x >> 3;
  const int q0 = qt * 64;
  const int tid = threadIdx.x;
  const int wave = tid >> 6;
  const int lane = tid & 63;
  const int lrow = lane & 15;
  const int g = lane >> 4;

  const u16* __restrict__ Qg = qb + ((size_t)h * NFULL + q0) * 64;
  const u16* __restrict__ Kg = kb + (size_t)h * NFULL * 64 + (wave * 16 + lrow) * 64 + g * 8;

  bf16x8 qf[4][2];
#pragma unroll
  for (int f = 0; f < 4; ++f) {
    qf[f][0] = *(const bf16x8*)&Qg[(f * 16 + lrow) * 64 + g * 8];
    qf[f][1] = *(const bf16x8*)&Qg[(f * 16 + lrow) * 64 + 32 + g * 8];
  }

  float dsum[4] = {0.f, 0.f, 0.f, 0.f};
  bf16x8 kf0 = *(const bf16x8*)(Kg);
  bf16x8 kf1 = *(const bf16x8*)(Kg + 32);

  for (int kt = 0; kt < 64; ++kt) {
    bf16x8 nk0, nk1;
    if (kt < 63) {  // prefetch next key-group fragment
      nk0 = *(const bf16x8*)(Kg + (kt + 1) * 4096);
      nk1 = *(const bf16x8*)(Kg + (kt + 1) * 4096 + 32);
    }
    f32x4 acc[4];
#pragma unroll
    for (int f = 0; f < 4; ++f) {
      f32x4 a = {0.f, 0.f, 0.f, 0.f};
      a = __builtin_amdgcn_mfma_f32_16x16x32_bf16(kf0, qf[f][0], a, 0, 0, 0);
      a = __builtin_amdgcn_mfma_f32_16x16x32_bf16(kf1, qf[f][1], a, 0, 0, 0);
      acc[f] = a;
    }
    const bool dg = (kt == qt);
#pragma unroll
    for (int f = 0; f < 4; ++f) {
      const float e0 = EXP2(acc[f][0]);
      const float e1 = EXP2(acc[f][1]);
      const float e2 = EXP2(acc[f][2]);
      const float e3 = EXP2(acc[f][3]);
      dsum[f] += (e0 + e1) + (e2 + e3);
      if (dg && f == wave) {  // diagonal 16x16 subtile: key grp == query grp
        const int rr = g * 4;
        P_lds[wave][rr + 0][lrow] = (rr + 0 <= lrow) ? e0 : 0.f;
        P_lds[wave][rr + 1][lrow] = (rr + 1 <= lrow) ? e1 : 0.f;
        P_lds[wave][rr + 2][lrow] = (rr + 2 <= lrow) ? e2 : 0.f;
        P_lds[wave][rr + 3][lrow] = (rr + 3 <= lrow) ? e3 : 0.f;
      }
    }
    kf0 = nk0; kf1 = nk1;
  }

#pragma unroll
  for (int f = 0; f < 4; ++f) {  // reduce over key-row groups (g)
    dsum[f] += __shfl_xor(dsum[f], 16);
    dsum[f] += __shfl_xor(dsum[f], 32);
  }
  if (g == 0) {
#pragma unroll
    for (int f = 0; f < 4; ++f) Ds[wave][f][lrow] = dsum[f];
  }
  __syncthreads();
  const float inv = 1.0f / (Ds[0][wave][lrow] + Ds[1][wave][lrow] +
                            Ds[2][wave][lrow] + Ds[3][wave][lrow]);

  // PV: 16 keys of own diagonal block, V direct from global (L2-hot)
  const float* __restrict__ V = vh + ((size_t)h * NFULL + q0 + wave * 16) * 64 + g * 16;
  float o[16];
#pragma unroll
  for (int dd = 0; dd < 16; ++dd) o[dd] = 0.f;
#pragma unroll
  for (int k = 0; k < 16; ++k) {
    const float p = P_lds[wave][k][lrow];
    const float4 v0 = *(const float4*)&V[k * 64 + 0];
    const float4 v1 = *(const float4*)&V[k * 64 + 4];
    const float4 v2 = *(const float4*)&V[k * 64 + 8];
    const float4 v3 = *(const float4*)&V[k * 64 + 12];
    o[0] += p * v0.x;  o[1] += p * v0.y;  o[2] += p * v0.z;  o[3] += p * v0.w;
    o[4] += p * v1.x;  o[5] += p * v1.y;  o[6] += p * v1.z;  o[7] += p * v1.w;
    o[8] += p * v2.x;  o[9] += p * v2.y;  o[10] += p * v2.z; o[11] += p * v2.w;
    o[12] += p * v3.x; o[13] += p * v3.y; o[14] += p * v3.z; o[15] += p * v3.w;
  }
  u16 ob[16];
#pragma unroll
  for (int dd = 0; dd < 16; ++dd) ob[dd] = f2bf(o[dd] * inv);
  const int qglob = q0 + wave * 16 + lrow;
  u16* __restrict__ op = wv + (size_t)qglob * CDIM + h * 64 + g * 16;
  *(uint4*)&op[0] = *(const uint4*)&ob[0];
  *(uint4*)&op[8] = *(const uint4*)&ob[8];
}

// K4: y = wv @ pwbf^T + bias2 + x, bf16 MFMA, prefetched staging. Grid 512.
__global__ __launch_bounds__(256) void k_dyn(const u16* __restrict__ wv,
                                             const float* __restrict__ x,
                                             const u16* __restrict__ pwbf,
                                             const float* __restrict__ bias2,
                                             float* __restrict__ y) {
  __shared__ __align__(16) u16 Ab[64][72];
  __shared__ __align__(16) u16 Wb[64][72];
  const int rb = blockIdx.x >> 3, cb = blockIdx.x & 7;
  const int r0 = rb * 64, c0 = cb * 64;
  const int tid = threadIdx.x;
  const int wave = tid >> 6, lane = tid & 63;
  const int lrow = lane & 15, g = lane >> 4;
  const int srow = tid >> 2;
  const int skc = (tid & 3) * 16;

  f32x4 acc[4];
#pragma unroll
  for (int ct = 0; ct < 4; ++ct) acc[ct] = (f32x4){0.f, 0.f, 0.f, 0.f};

  const u16* ap = wv + (size_t)(r0 + srow) * 512 + skc;
  const u16* wp = pwbf + (size_t)(c0 + srow) * 512 + skc;
  uint4 a0 = *(const uint4*)ap;
  uint4 a1 = *(const uint4*)(ap + 8);
  uint4 w0 = *(const uint4*)wp;
  uint4 w1 = *(const uint4*)(wp + 8);

  for (int k0 = 0; k0 < 512; k0 += 64) {
    __syncthreads();
    *(uint4*)&Ab[srow][skc] = a0;
    *(uint4*)&Ab[srow][skc + 8] = a1;
    *(uint4*)&Wb[srow][skc] = w0;
    *(uint4*)&Wb[srow][skc + 8] = w1;
    __syncthreads();
    if (k0 + 64 < 512) {  // prefetch next tile under the MFMAs
      a0 = *(const uint4*)(ap + k0 + 64);
      a1 = *(const uint4*)(ap + k0 + 64 + 8);
      w0 = *(const uint4*)(wp + k0 + 64);
      w1 = *(const uint4*)(wp + k0 + 64 + 8);
    }
#pragma unroll
    for (int kk = 0; kk < 2; ++kk) {
      const bf16x8 af = *(const bf16x8*)&Ab[wave * 16 + lrow][kk * 32 + g * 8];
#pragma unroll
      for (int ct = 0; ct < 4; ++ct) {
        const bf16x8 wf = *(const bf16x8*)&Wb[ct * 16 + lrow][kk * 32 + g * 8];
        acc[ct] = __builtin_amdgcn_mfma_f32_16x16x32_bf16(wf, af, acc[ct], 0, 0, 0);
      }
    }
  }
  const int row = r0 + wave * 16 + lrow;
#pragma unroll
  for (int ct = 0; ct < 4; ++ct) {
    const int c = c0 + ct * 16 + g * 4;
    const float4 bb = *(const float4*)&bias2[c];
    const float4 xv = *(const float4*)&x[(size_t)row * 512 + c];
    float4 res;
    res.x = acc[ct][0] + bb.x + xv.x;
    res.y = acc[ct][1] + bb.y + xv.y;
    res.z = acc[ct][2] + bb.z + xv.z;
    res.w = acc[ct][3] + bb.w + xv.w;
    *(float4*)&y[(size_t)row * 512 + c] = res;
  }
}

// K5a: tp_part[ks][4096][32] = y @ p_w1^T over K chunk ks*64..+64. Grid 512.
__global__ __launch_bounds__(256) void k_pout1(const float* __restrict__ y,
                                               const float* __restrict__ pw1,
                                               float* __restrict__ tp_part) {
  __shared__ __align__(16) float As[16][68];
  __shared__ __align__(16) float Ws[16][36];
  const int rb = blockIdx.x >> 3;
  const int ks = blockIdx.x & 7;
  const int r0 = rb * 64;
  const int ty = threadIdx.x >> 4, tx = threadIdx.x & 15;
  const int lr = threadIdx.x >> 2;
  const int lk = (threadIdx.x & 3) << 2;
  float acc[4][2];
#pragma unroll
  for (int i = 0; i < 4; ++i) { acc[i][0] = 0.f; acc[i][1] = 0.f; }

  for (int k0 = ks * 64; k0 < ks * 64 + 64; k0 += 16) {
    const float4 a = *(const float4*)&y[(r0 + lr) * 512 + k0 + lk];
    float4 w;
    const int wc = threadIdx.x >> 2;
    if (threadIdx.x < 128) w = *(const float4*)&pw1[wc * 512 + k0 + lk];
    __syncthreads();
    As[lk + 0][lr] = a.x; As[lk + 1][lr] = a.y;
    As[lk + 2][lr] = a.z; As[lk + 3][lr] = a.w;
    if (threadIdx.x < 128) {
      Ws[lk + 0][wc] = w.x; Ws[lk + 1][wc] = w.y;
      Ws[lk + 2][wc] = w.z; Ws[lk + 3][wc] = w.w;
    }
    __syncthreads();
#pragma unroll
    for (int k = 0; k < 16; ++k) {
      const float4 av = *(const float4*)&As[k][ty * 4];
      const float ar[4] = {av.x, av.y, av.z, av.w};
      const float b0 = Ws[k][tx], b1 = Ws[k][tx + 16];
#pragma unroll
      for (int i = 0; i < 4; ++i) {
        acc[i][0] += ar[i] * b0;
        acc[i][1] += ar[i] * b1;
      }
    }
  }
  float* __restrict__ tp = tp_part + (size_t)ks * NFULL * 32;
#pragma unroll
  for (int i = 0; i < 4; ++i) {
    tp[(r0 + ty * 4 + i) * 32 + tx] = acc[i][0];
    tp[(r0 + ty * 4 + i) * 32 + tx + 16] = acc[i][1];
  }
}

// K5b: out = (sum of 8 tp partials) @ p_w2^T. Grid 2048.
__global__ __launch_bounds__(256) void k_pout2(const float* __restrict__ tp_part,
                                               const float* __restrict__ pw2,
                                               float* __restrict__ out) {
  __shared__ __align__(16) float ts[64][36];
  const int bc = blockIdx.x & 31;
  const int br = blockIdx.x >> 5;
  const int r0 = br * 64;
  for (int idx = threadIdx.x; idx < 512; idx += 256) {
    const int rr = idx >> 3;
    const int cc = (idx & 7) << 2;
    float4 s = {0.f, 0.f, 0.f, 0.f};
#pragma unroll
    for (int p = 0; p < 8; ++p) {
      const float4 v = *(const float4*)&tp_part[((size_t)p * NFULL + r0 + rr) * 32 + cc];
      s.x += v.x; s.y += v.y; s.z += v.z; s.w += v.w;
    }
    *(float4*)&ts[rr][cc] = s;
  }
  __syncthreads();
  const int tx = threadIdx.x & 15, ty = threadIdx.x >> 4;
  const int c = bc * 16 + tx;
  const float* __restrict__ w = pw2 + c * 32;
  float4 wr[8];
#pragma unroll
  for (int e = 0; e < 8; ++e) wr[e] = *(const float4*)&w[e * 4];
#pragma unroll
  for (int i = 0; i < 4; ++i) {
    const int r = ty * 4 + i;
    float acc = 0.f;
#pragma unroll
    for (int e = 0; e < 8; ++e) acc += dot4(*(const float4*)&ts[r][e * 4], wr[e]);
    out[(r0 + r) * 512 + c] = acc;
  }
}

extern "C" void kernel_launch(void* const* d_in, const int* in_sizes, int n_in,
                              void* d_out, int out_size, void* d_ws, size_t ws_size,
                              hipStream_t stream) {
  const float* x     = (const float*)d_in[0];
  const float* q_w1  = (const float*)d_in[1];
  const float* q_w2  = (const float*)d_in[2];
  const float* kv_w1 = (const float*)d_in[3];
  const float* kv_w2 = (const float*)d_in[4];
  const float* dw_w  = (const float*)d_in[5];
  const float* dw_b  = (const float*)d_in[6];
  const float* pw_w  = (const float*)d_in[7];
  const float* pw_b  = (const float*)d_in[8];
  const float* p_w1  = (const float*)d_in[9];
  const float* p_w2  = (const float*)d_in[10];
  float* out = (float*)d_out;

  char* ws = (char*)d_ws;
  float* t     = (float*)ws;                                  // 4096*96 f32
  float* bias2 = t + NFULL * 96;                              // 1024 f32
  u16*   pwbf  = (u16*)(bias2 + 1024);                        // 512*512 u16
  u16*   qbw   = pwbf + 512 * 512;                            // 2M u16
  u16*   kbw   = qbw + (size_t)HEADS * NFULL * DDIM;          // 2M u16
  float* vh    = (float*)(kbw + (size_t)HEADS * NFULL * DDIM);// 2M f32
  u16*   wv16  = (u16*)(vh + (size_t)HEADS * NFULL * DDIM);   // 2M u16
  float* y     = (float*)(wv16 + (size_t)NFULL * CDIM);       // 2M f32
  // t_part (8*4096*96 f32 = 12.58 MB) aliases vh+wv16 exactly (3145728 f32);
  // both are written only after k_tred has consumed t_part.
  float* t_part = vh;
  // tp_part (8*4096*32 f32 = 4 MB) aliases qbw (dead after k_attn).
  float* tp_part = (float*)qbw;

  k_proj1<<<512, 256, 0, stream>>>(x, q_w1, kv_w1, t_part);
  k_tred<<<450, 256, 0, stream>>>(t_part, t, pw_w, dw_w, dw_b, pw_b, bias2, pwbf);
  k_proj2<<<(NFULL / 64) * 96, 256, 0, stream>>>(t, q_w2, kv_w2, qbw, kbw, vh);
  k_attn<<<HEADS * (NFULL / 64), 256, 0, stream>>>(qbw, kbw, vh, wv16);
  k_dyn<<<(NFULL / 64) * 8, 256, 0, stream>>>(wv16, x, pwbf, bias2, y);
  k_pout1<<<512, 256, 0, stream>>>(y, p_w1, tp_part);
  k_pout2<<<(NFULL / 64) * 32, 256, 0, stream>>>(tp_part, p_w2, out);
}

// Round 6
// 122.352 us; speedup vs baseline: 9.4184x; 1.0233x over previous
//
#include <hip/hip_runtime.h>

#define NFULL 4096
#define CDIM  512
#define HEADS 8
#define DDIM  64

typedef unsigned short u16;
typedef short bf16x8 __attribute__((ext_vector_type(8)));
typedef float f32x4 __attribute__((ext_vector_type(4)));

#if __has_builtin(__builtin_amdgcn_exp2f)
#define EXP2(x) __builtin_amdgcn_exp2f(x)
#else
#define EXP2(x) exp2f(x)
#endif

// q is pre-scaled by SCALE * log2(e) so softmax exp(s) == exp2(s').
#define QSCALE 11.541560327111707f  // 8 * 1.4426950408889634

__device__ __forceinline__ float dot4(float4 a, float4 b) {
  return a.x * b.x + a.y * b.y + a.z * b.z + a.w * b.w;
}

__device__ __forceinline__ u16 f2bf(float x) {  // RNE f32 -> bf16 bits
  union { float f; unsigned u; } v; v.f = x;
  unsigned r = v.u + 0x7fffu + ((v.u >> 16) & 1u);
  return (u16)(r >> 16);
}

// K1: t_part[ks][4096][96] = x @ [q_w1; kv_w1]^T over K chunk ks*64..+64.
__global__ __launch_bounds__(256) void k_proj1(const float* __restrict__ x,
                                               const float* __restrict__ qw1,
                                               const float* __restrict__ kvw1,
                                               float* __restrict__ t_part) {
  __shared__ __align__(16) float As[16][68];   // [k][row]
  __shared__ __align__(16) float Ws[16][100];  // [k][col 0..95]
  const int rb = blockIdx.x >> 3;
  const int ks = blockIdx.x & 7;
  const int r0 = rb * 64;
  const int ty = threadIdx.x >> 4, tx = threadIdx.x & 15;
  const int lr = threadIdx.x >> 2;
  const int lk = (threadIdx.x & 3) << 2;
  float acc[4][6];
#pragma unroll
  for (int i = 0; i < 4; ++i)
#pragma unroll
    for (int j = 0; j < 6; ++j) acc[i][j] = 0.f;

  for (int k0 = ks * 64; k0 < ks * 64 + 64; k0 += 16) {
    __syncthreads();
    {
      const float4 a = *(const float4*)&x[(r0 + lr) * 512 + k0 + lk];
      As[lk + 0][lr] = a.x; As[lk + 1][lr] = a.y;
      As[lk + 2][lr] = a.z; As[lk + 3][lr] = a.w;
    }
    for (int idx = threadIdx.x; idx < 384; idx += 256) {
      const int c = idx >> 2;
      const int kk = (idx & 3) << 2;
      const float* __restrict__ wsrc = (c < 32) ? (qw1 + c * 512) : (kvw1 + (c - 32) * 512);
      const float4 w = *(const float4*)&wsrc[k0 + kk];
      Ws[kk + 0][c] = w.x; Ws[kk + 1][c] = w.y;
      Ws[kk + 2][c] = w.z; Ws[kk + 3][c] = w.w;
    }
    __syncthreads();
#pragma unroll
    for (int k = 0; k < 16; ++k) {
      const float4 a = *(const float4*)&As[k][ty * 4];
      const float ar[4] = {a.x, a.y, a.z, a.w};
      float br[6];
#pragma unroll
      for (int j = 0; j < 6; ++j) br[j] = Ws[k][tx + 16 * j];
#pragma unroll
      for (int i = 0; i < 4; ++i)
#pragma unroll
        for (int j = 0; j < 6; ++j) acc[i][j] += ar[i] * br[j];
    }
  }
  float* __restrict__ tp = t_part + (size_t)ks * NFULL * 96;
#pragma unroll
  for (int i = 0; i < 4; ++i)
#pragma unroll
    for (int j = 0; j < 6; ++j)
      tp[(r0 + ty * 4 + i) * 96 + tx + 16 * j] = acc[i][j];
}

// K1b: blocks 0..383: t = sum of 8 partials. 384..385: bias2. 386..449: pwbf.
__global__ __launch_bounds__(256) void k_tred(const float* __restrict__ t_part,
                                              float* __restrict__ t,
                                              const float* __restrict__ pww,
                                              const float* __restrict__ dww,
                                              const float* __restrict__ dwb,
                                              const float* __restrict__ pwb,
                                              float* __restrict__ bias2,
                                              u16* __restrict__ pwbf) {
  const int b = blockIdx.x;
  if (b < 384) {
    const int i = b * 256 + threadIdx.x;
    const float4* __restrict__ src = (const float4*)t_part;
    float4 s = src[i];
#pragma unroll
    for (int p = 1; p < 8; ++p) {
      const float4 v = src[(size_t)p * 98304 + i];
      s.x += v.x; s.y += v.y; s.z += v.z; s.w += v.w;
    }
    ((float4*)t)[i] = s;
  } else if (b < 386) {
    const int c = (b - 384) * 256 + threadIdx.x;
    float acc = 0.f;
    for (int e = 0; e < 512; e += 4)
      acc += dot4(*(const float4*)&pww[c * 512 + e], *(const float4*)&dwb[e]);
    bias2[c] = acc + pwb[c];
  } else {
    const int base = (b - 386) * 4096 + threadIdx.x * 16;
    const int e0 = base & 511;
    u16 o[16];
#pragma unroll
    for (int q = 0; q < 4; ++q) {
      const float4 w = *(const float4*)&pww[base + q * 4];
      const float4 d = *(const float4*)&dww[e0 + q * 4];
      o[q * 4 + 0] = f2bf(w.x * d.x);
      o[q * 4 + 1] = f2bf(w.y * d.y);
      o[q * 4 + 2] = f2bf(w.z * d.z);
      o[q * 4 + 3] = f2bf(w.w * d.w);
    }
    *(uint4*)&pwbf[base] = *(const uint4*)&o[0];
    *(uint4*)&pwbf[base + 8] = *(const uint4*)&o[8];
  }
}

// K2: qb = bf16(QSCALE * t_q @ q_w2^T); kb = bf16(kv half 1); vh = f32 (half 2).
__global__ __launch_bounds__(256) void k_proj2(const float* __restrict__ t,
                                               const float* __restrict__ qw2,
                                               const float* __restrict__ kvw2,
                                               u16* __restrict__ qb,
                                               u16* __restrict__ kb,
                                               float* __restrict__ vh) {
  __shared__ __align__(16) float ts[64][100];
  __shared__ __align__(16) float Wl[16][68];
  const int bc = blockIdx.x % 96;
  const int br = blockIdx.x / 96;
  const int r0 = br * 64;
  for (int idx = threadIdx.x; idx < 1536; idx += 256) {
    const int rr = idx / 24;
    const int cc = (idx - rr * 24) * 4;
    *(float4*)&ts[rr][cc] = *(const float4*)&t[(r0 + rr) * 96 + cc];
  }
  const int cbase = bc * 16;
  if (cbase < 512) {
    if (threadIdx.x < 128) {
      const int col = threadIdx.x >> 3;
      const int ko = (threadIdx.x & 7) * 4;
      *(float4*)&Wl[col][ko] = *(const float4*)&qw2[(cbase + col) * 32 + ko];
    }
  } else {
    const int col = threadIdx.x >> 4;
    const int ko = (threadIdx.x & 15) * 4;
    *(float4*)&Wl[col][ko] = *(const float4*)&kvw2[(cbase - 512 + col) * 64 + ko];
  }
  __syncthreads();
  const int tx = threadIdx.x & 15, ty = threadIdx.x >> 4;
  const int c = cbase + tx;
  if (c < 512) {
    float4 wr[8];
#pragma unroll
    for (int e = 0; e < 8; ++e) wr[e] = *(const float4*)&Wl[tx][e * 4];
    const int h = c >> 6, d = c & 63;
#pragma unroll
    for (int i = 0; i < 4; ++i) {
      const int r = ty * 4 + i;
      float acc = 0.f;
#pragma unroll
      for (int e = 0; e < 8; ++e) acc += dot4(*(const float4*)&ts[r][e * 4], wr[e]);
      qb[(h * NFULL + r0 + r) * 64 + d] = f2bf(acc * QSCALE);
    }
  } else {
    float4 wr[16];
#pragma unroll
    for (int e = 0; e < 16; ++e) wr[e] = *(const float4*)&Wl[tx][e * 4];
    const int cc = c - 512;
    const int c2 = cc & 511;
    const int h = c2 >> 6, d = c2 & 63;
#pragma unroll
    for (int i = 0; i < 4; ++i) {
      const int r = ty * 4 + i;
      float acc = 0.f;
#pragma unroll
      for (int e = 0; e < 16; ++e) acc += dot4(*(const float4*)&ts[r][32 + e * 4], wr[e]);
      if (cc < 512)
        kb[(h * NFULL + r0 + r) * 64 + d] = f2bf(acc);
      else
        vh[(h * NFULL + r0 + r) * 64 + d] = acc;
    }
  }
}

// K3: LDS-free MFMA attention, key-split x2. Block (h, qt, s) sums exp over
// keys [s*2048, s*2048+2048); partial denom -> dsp[s][h][row]. The block with
// s == qt>>5 owns the diagonal and writes UNNORMALIZED o (f32) to wv.
__global__ __launch_bounds__(256) void k_attn(const u16* __restrict__ qb,
                                              const u16* __restrict__ kb,
                                              const float* __restrict__ vh,
                                              float* __restrict__ wv,
                                              float* __restrict__ dsp) {
  __shared__ float P_lds[4][16][17];
  __shared__ float Ds[4][4][16];
  const int h = blockIdx.x & 7;
  const int qt = (blockIdx.x >> 3) & 63;
  const int s = blockIdx.x >> 9;
  const int q0 = qt * 64;
  const int tid = threadIdx.x;
  const int wave = tid >> 6;
  const int lane = tid & 63;
  const int lrow = lane & 15;
  const int g = lane >> 4;

  const u16* __restrict__ Qg = qb + ((size_t)h * NFULL + q0) * 64;
  const u16* __restrict__ Kg = kb + (size_t)h * NFULL * 64 + (wave * 16 + lrow) * 64 + g * 8;

  bf16x8 qf[4][2];
#pragma unroll
  for (int f = 0; f < 4; ++f) {
    qf[f][0] = *(const bf16x8*)&Qg[(f * 16 + lrow) * 64 + g * 8];
    qf[f][1] = *(const bf16x8*)&Qg[(f * 16 + lrow) * 64 + 32 + g * 8];
  }

  float dsum[4] = {0.f, 0.f, 0.f, 0.f};
  const int kt0 = s * 32;

  auto body = [&](bf16x8 kf0, bf16x8 kf1, int kt) {
    f32x4 a[4];
#pragma unroll
    for (int f = 0; f < 4; ++f) {
      f32x4 t4 = {0.f, 0.f, 0.f, 0.f};
      t4 = __builtin_amdgcn_mfma_f32_16x16x32_bf16(kf0, qf[f][0], t4, 0, 0, 0);
      t4 = __builtin_amdgcn_mfma_f32_16x16x32_bf16(kf1, qf[f][1], t4, 0, 0, 0);
      a[f] = t4;
    }
    const bool dg = (kt == qt);
#pragma unroll
    for (int f = 0; f < 4; ++f) {
      const float e0 = EXP2(a[f][0]);
      const float e1 = EXP2(a[f][1]);
      const float e2 = EXP2(a[f][2]);
      const float e3 = EXP2(a[f][3]);
      dsum[f] += (e0 + e1) + (e2 + e3);
      if (dg && f == wave) {
        const int rr = g * 4;
        P_lds[wave][rr + 0][lrow] = (rr + 0 <= lrow) ? e0 : 0.f;
        P_lds[wave][rr + 1][lrow] = (rr + 1 <= lrow) ? e1 : 0.f;
        P_lds[wave][rr + 2][lrow] = (rr + 2 <= lrow) ? e2 : 0.f;
        P_lds[wave][rr + 3][lrow] = (rr + 3 <= lrow) ? e3 : 0.f;
      }
    }
  };

  bf16x8 c0a = *(const bf16x8*)(Kg + (size_t)(kt0 + 0) * 4096);
  bf16x8 c0b = *(const bf16x8*)(Kg + (size_t)(kt0 + 0) * 4096 + 32);
  bf16x8 c1a = *(const bf16x8*)(Kg + (size_t)(kt0 + 1) * 4096);
  bf16x8 c1b = *(const bf16x8*)(Kg + (size_t)(kt0 + 1) * 4096 + 32);

  for (int kt = kt0; kt < kt0 + 30; kt += 2) {  // depth-2 rolling prefetch
    const bf16x8 n0a = *(const bf16x8*)(Kg + (size_t)(kt + 2) * 4096);
    const bf16x8 n0b = *(const bf16x8*)(Kg + (size_t)(kt + 2) * 4096 + 32);
    const bf16x8 n1a = *(const bf16x8*)(Kg + (size_t)(kt + 3) * 4096);
    const bf16x8 n1b = *(const bf16x8*)(Kg + (size_t)(kt + 3) * 4096 + 32);
    body(c0a, c0b, kt);
    body(c1a, c1b, kt + 1);
    c0a = n0a; c0b = n0b; c1a = n1a; c1b = n1b;
  }
  body(c0a, c0b, kt0 + 30);
  body(c1a, c1b, kt0 + 31);

#pragma unroll
  for (int f = 0; f < 4; ++f) {
    dsum[f] += __shfl_xor(dsum[f], 16);
    dsum[f] += __shfl_xor(dsum[f], 32);
  }
  if (g == 0) {
#pragma unroll
    for (int f = 0; f < 4; ++f) Ds[wave][f][lrow] = dsum[f];
  }
  __syncthreads();
  const float den = Ds[0][wave][lrow] + Ds[1][wave][lrow] +
                    Ds[2][wave][lrow] + Ds[3][wave][lrow];
  if (g == 0)
    dsp[((size_t)s * HEADS + h) * NFULL + q0 + wave * 16 + lrow] = den;

  if (s == (qt >> 5)) {  // diagonal-owning split: PV numerator, unnormalized
    const float* __restrict__ V = vh + ((size_t)h * NFULL + q0 + wave * 16) * 64 + g * 16;
    float o[16];
#pragma unroll
    for (int dd = 0; dd < 16; ++dd) o[dd] = 0.f;
#pragma unroll
    for (int k = 0; k < 16; ++k) {
      const float p = P_lds[wave][k][lrow];
      const float4 v0 = *(const float4*)&V[k * 64 + 0];
      const float4 v1 = *(const float4*)&V[k * 64 + 4];
      const float4 v2 = *(const float4*)&V[k * 64 + 8];
      const float4 v3 = *(const float4*)&V[k * 64 + 12];
      o[0] += p * v0.x;  o[1] += p * v0.y;  o[2] += p * v0.z;  o[3] += p * v0.w;
      o[4] += p * v1.x;  o[5] += p * v1.y;  o[6] += p * v1.z;  o[7] += p * v1.w;
      o[8] += p * v2.x;  o[9] += p * v2.y;  o[10] += p * v2.z; o[11] += p * v2.w;
      o[12] += p * v3.x; o[13] += p * v3.y; o[14] += p * v3.z; o[15] += p * v3.w;
    }
    float* __restrict__ op = wv + (size_t)(q0 + wave * 16 + lrow) * CDIM + h * 64 + g * 16;
#pragma unroll
    for (int c4 = 0; c4 < 4; ++c4) {
      float4 r;
      r.x = o[c4 * 4 + 0]; r.y = o[c4 * 4 + 1];
      r.z = o[c4 * 4 + 2]; r.w = o[c4 * 4 + 3];
      *(float4*)&op[c4 * 4] = r;
    }
  }
}

// K4: y = softmax-normalize(wv) @ pwbf^T + bias2 + x. Normalization (per row,
// per head) folded into the bf16 staging convert. Grid 512.
__global__ __launch_bounds__(256) void k_dyn(const float* __restrict__ wv,
                                             const float* __restrict__ x,
                                             const u16* __restrict__ pwbf,
                                             const float* __restrict__ bias2,
                                             const float* __restrict__ dsp,
                                             float* __restrict__ y) {
  __shared__ __align__(16) u16 Ab[64][72];
  __shared__ __align__(16) u16 Wb[64][72];
  const int rb = blockIdx.x >> 3, cb = blockIdx.x & 7;
  const int r0 = rb * 64, c0 = cb * 64;
  const int tid = threadIdx.x;
  const int wave = tid >> 6, lane = tid & 63;
  const int lrow = lane & 15, g = lane >> 4;
  const int srow = tid >> 2;
  const int skc = (tid & 3) * 16;

  float inv8[8];
#pragma unroll
  for (int hh = 0; hh < 8; ++hh)
    inv8[hh] = 1.0f / (dsp[(size_t)hh * NFULL + r0 + srow] +
                       dsp[(size_t)(8 + hh) * NFULL + r0 + srow]);

  f32x4 acc[4];
#pragma unroll
  for (int ct = 0; ct < 4; ++ct) acc[ct] = (f32x4){0.f, 0.f, 0.f, 0.f};

  const float* __restrict__ ap = wv + (size_t)(r0 + srow) * 512 + skc;
  const u16* __restrict__ wp = pwbf + (size_t)(c0 + srow) * 512 + skc;
  float4 a4[4];
#pragma unroll
  for (int e = 0; e < 4; ++e) a4[e] = *(const float4*)(ap + e * 4);
  uint4 w0 = *(const uint4*)wp;
  uint4 w1 = *(const uint4*)(wp + 8);

  for (int k0 = 0; k0 < 512; k0 += 64) {
    const float sc = inv8[k0 >> 6];
    u16 ab16[16];
#pragma unroll
    for (int e = 0; e < 4; ++e) {
      ab16[e * 4 + 0] = f2bf(a4[e].x * sc);
      ab16[e * 4 + 1] = f2bf(a4[e].y * sc);
      ab16[e * 4 + 2] = f2bf(a4[e].z * sc);
      ab16[e * 4 + 3] = f2bf(a4[e].w * sc);
    }
    __syncthreads();
    *(uint4*)&Ab[srow][skc] = *(const uint4*)&ab16[0];
    *(uint4*)&Ab[srow][skc + 8] = *(const uint4*)&ab16[8];
    *(uint4*)&Wb[srow][skc] = w0;
    *(uint4*)&Wb[srow][skc + 8] = w1;
    __syncthreads();
    if (k0 + 64 < 512) {
#pragma unroll
      for (int e = 0; e < 4; ++e) a4[e] = *(const float4*)(ap + k0 + 64 + e * 4);
      w0 = *(const uint4*)(wp + k0 + 64);
      w1 = *(const uint4*)(wp + k0 + 64 + 8);
    }
#pragma unroll
    for (int kk = 0; kk < 2; ++kk) {
      const bf16x8 af = *(const bf16x8*)&Ab[wave * 16 + lrow][kk * 32 + g * 8];
#pragma unroll
      for (int ct = 0; ct < 4; ++ct) {
        const bf16x8 wf = *(const bf16x8*)&Wb[ct * 16 + lrow][kk * 32 + g * 8];
        acc[ct] = __builtin_amdgcn_mfma_f32_16x16x32_bf16(wf, af, acc[ct], 0, 0, 0);
      }
    }
  }
  const int row = r0 + wave * 16 + lrow;
#pragma unroll
  for (int ct = 0; ct < 4; ++ct) {
    const int c = c0 + ct * 16 + g * 4;
    const float4 bb = *(const float4*)&bias2[c];
    const float4 xv = *(const float4*)&x[(size_t)row * 512 + c];
    float4 res;
    res.x = acc[ct][0] + bb.x + xv.x;
    res.y = acc[ct][1] + bb.y + xv.y;
    res.z = acc[ct][2] + bb.z + xv.z;
    res.w = acc[ct][3] + bb.w + xv.w;
    *(float4*)&y[(size_t)row * 512 + c] = res;
  }
}

// K5: out[16 rows] = ((y @ p_w1^T) @ p_w2^T) via MFMA, fused. Grid 256.
// Phase1: tp[16][32] (2-way K-split across wave pairs, LDS-reduced).
// Phase2: out[16][512], w2 A-frags direct from global with bf16 convert.
__global__ __launch_bounds__(256) void k_pout(const float* __restrict__ y,
                                              const float* __restrict__ pw1,
                                              const float* __restrict__ pw2,
                                              float* __restrict__ out) {
  __shared__ __align__(16) u16 yb[16][520];
  __shared__ float tp_part[2][32][17];
  const int r0 = blockIdx.x * 16;
  const int tid = threadIdx.x;
  const int wave = tid >> 6, lane = tid & 63;
  const int lrow = lane & 15, g = lane >> 4;

  // stage y rows -> bf16 LDS (2048 float4)
  for (int rep = 0; rep < 8; ++rep) {
    const int l = rep * 256 + tid;
    const int row = l >> 7, c4 = (l & 127) << 2;
    const float4 v = *(const float4*)&y[(size_t)(r0 + row) * 512 + c4];
    yb[row][c4 + 0] = f2bf(v.x); yb[row][c4 + 1] = f2bf(v.y);
    yb[row][c4 + 2] = f2bf(v.z); yb[row][c4 + 3] = f2bf(v.w);
  }
  __syncthreads();

  {  // phase 1: wave = (kh<<1)|ct1 ; K-half kh covers 256, ctile ct1 covers 16 tp cols
    const int ct1 = wave & 1, kh = wave >> 1;
    f32x4 acc = {0.f, 0.f, 0.f, 0.f};
#pragma unroll
    for (int ks = 0; ks < 8; ++ks) {
      const int K = kh * 256 + ks * 32 + g * 8;
      union { u16 a[8]; bf16x8 v; } aw;
      const float4 wv0 = *(const float4*)&pw1[(size_t)(ct1 * 16 + lrow) * 512 + K];
      const float4 wv1 = *(const float4*)&pw1[(size_t)(ct1 * 16 + lrow) * 512 + K + 4];
      aw.a[0] = f2bf(wv0.x); aw.a[1] = f2bf(wv0.y);
      aw.a[2] = f2bf(wv0.z); aw.a[3] = f2bf(wv0.w);
      aw.a[4] = f2bf(wv1.x); aw.a[5] = f2bf(wv1.y);
      aw.a[6] = f2bf(wv1.z); aw.a[7] = f2bf(wv1.w);
      const bf16x8 bf = *(const bf16x8*)&yb[lrow][K];
      acc = __builtin_amdgcn_mfma_f32_16x16x32_bf16(aw.v, bf, acc, 0, 0, 0);
    }
#pragma unroll
    for (int j = 0; j < 4; ++j)
      tp_part[kh][ct1 * 16 + g * 4 + j][lrow] = acc[j];
  }
  __syncthreads();

  // tp B-fragment: lane holds tp[row=lrow][k=g*8..+8]
  union { u16 a[8]; bf16x8 v; } bq;
#pragma unroll
  for (int i = 0; i < 8; ++i) {
    const int k = g * 8 + i;
    bq.a[i] = f2bf(tp_part[0][k][lrow] + tp_part[1][k][lrow]);
  }

  // phase 2: 8 col-tiles per wave, K=32 in one MFMA
#pragma unroll
  for (int t = 0; t < 8; ++t) {
    const int ct = wave * 8 + t;
    union { u16 a[8]; bf16x8 v; } aw;
    const float4 wv0 = *(const float4*)&pw2[(size_t)(ct * 16 + lrow) * 32 + g * 8];
    const float4 wv1 = *(const float4*)&pw2[(size_t)(ct * 16 + lrow) * 32 + g * 8 + 4];
    aw.a[0] = f2bf(wv0.x); aw.a[1] = f2bf(wv0.y);
    aw.a[2] = f2bf(wv0.z); aw.a[3] = f2bf(wv0.w);
    aw.a[4] = f2bf(wv1.x); aw.a[5] = f2bf(wv1.y);
    aw.a[6] = f2bf(wv1.z); aw.a[7] = f2bf(wv1.w);
    f32x4 acc = {0.f, 0.f, 0.f, 0.f};
    acc = __builtin_amdgcn_mfma_f32_16x16x32_bf16(aw.v, bq.v, acc, 0, 0, 0);
    float4 res;
    res.x = acc[0]; res.y = acc[1]; res.z = acc[2]; res.w = acc[3];
    *(float4*)&out[(size_t)(r0 + lrow) * 512 + ct * 16 + g * 4] = res;
  }
}

extern "C" void kernel_launch(void* const* d_in, const int* in_sizes, int n_in,
                              void* d_out, int out_size, void* d_ws, size_t ws_size,
                              hipStream_t stream) {
  const float* x     = (const float*)d_in[0];
  const float* q_w1  = (const float*)d_in[1];
  const float* q_w2  = (const float*)d_in[2];
  const float* kv_w1 = (const float*)d_in[3];
  const float* kv_w2 = (const float*)d_in[4];
  const float* dw_w  = (const float*)d_in[5];
  const float* dw_b  = (const float*)d_in[6];
  const float* pw_w  = (const float*)d_in[7];
  const float* pw_b  = (const float*)d_in[8];
  const float* p_w1  = (const float*)d_in[9];
  const float* p_w2  = (const float*)d_in[10];
  float* out = (float*)d_out;

  char* ws = (char*)d_ws;
  float* t     = (float*)ws;                                   // 4096*96 f32
  float* bias2 = t + NFULL * 96;                               // 1024 f32
  u16*   pwbf  = (u16*)(bias2 + 1024);                         // 512*512 u16
  u16*   qbw   = pwbf + 512 * 512;                             // 2M u16
  u16*   kbw   = qbw + (size_t)HEADS * NFULL * DDIM;           // 2M u16
  float* vh    = (float*)(kbw + (size_t)HEADS * NFULL * DDIM); // 2M f32
  float* wvf   = vh + (size_t)HEADS * NFULL * DDIM;            // 2M f32
  float* y     = wvf + (size_t)NFULL * CDIM;                   // 2M f32
  float* dsp   = y + (size_t)NFULL * CDIM;                     // 2*8*4096 f32
  // t_part (8*4096*96 = 3,145,728 f32) aliases vh(2M)+wvf(first 1.1M); both
  // are written only after k_tred has consumed t_part.
  float* t_part = vh;

  k_proj1<<<512, 256, 0, stream>>>(x, q_w1, kv_w1, t_part);
  k_tred<<<450, 256, 0, stream>>>(t_part, t, pw_w, dw_w, dw_b, pw_b, bias2, pwbf);
  k_proj2<<<(NFULL / 64) * 96, 256, 0, stream>>>(t, q_w2, kv_w2, qbw, kbw, vh);
  k_attn<<<2 * HEADS * (NFULL / 64), 256, 0, stream>>>(qbw, kbw, vh, wvf, dsp);
  k_dyn<<<(NFULL / 64) * 8, 256, 0, stream>>>(wvf, x, pwbf, bias2, dsp, y);
  k_pout<<<NFULL / 16, 256, 0, stream>>>(y, p_w1, p_w2, out);
}